// Round 11
// baseline (674.590 us; speedup 1.0000x reference)
//
#include <hip/hip_runtime.h>
#include <math.h>

typedef __attribute__((ext_vector_type(8))) short short8;   // 8 bf16 (4 VGPR) MFMA A/B frag
typedef __attribute__((ext_vector_type(4))) float f32x4;    // MFMA C/D frag
typedef __attribute__((ext_vector_type(4))) uint  uint4v;

constexpr int Bb = 1024, Nn = 100, Hh = 4, Oo = 32, Dd = 128;
constexpr int K1 = 12800, N1 = 1024, M1 = 1024, SK = 8;

// bf16 round-to-nearest-even helpers
__device__ __forceinline__ ushort f2bf(float f) {
    uint u = __float_as_uint(f);
    return (ushort)((u + 0x7FFFu + ((u >> 16) & 1u)) >> 16);
}
__device__ __forceinline__ float bf2f(ushort h) {
    return __uint_as_float(((uint)h) << 16);
}
__device__ __forceinline__ short8 mk8(uint a, uint b, uint c, uint d) {
    uint4v v = {a, b, c, d};
    return __builtin_bit_cast(short8, v);
}
__device__ __forceinline__ short8 u4s8(uint4 v) {
    uint4v t = {v.x, v.y, v.z, v.w};
    return __builtin_bit_cast(short8, t);
}
// swizzle within [rows][256B] LDS tiles: XOR 16B-slot bits with row&7
__device__ __forceinline__ int swzb(int row, int kb)  { return row * 256 + (kb ^ ((row & 7) << 4)); }

// GAT LDS layout (dynamic, 36352 B)
#define OFF_HTH 0        /* hT hi [32][256B] */
#define OFF_HTL 8192
#define OFF_WTH 16384    /* WT hi [32][256B] */
#define OFF_WTL 24576
#define OFF_AB  32768    /* adjacency bitmask [112][4 u32] (448 words, >=400 zeroed) */
#define OFF_ASV 34560    /* a-vector 64 f32 */
#define OFF_ESV 34816    /* e_src [128] f32 */
#define OFF_EDV 35328    /* e_dst [128] f32 */
#define OFF_INV 35840    /* 1/rowsum [128] f32 */
#define GAT_LDS 36352

// ---------------------------------------------------------------------------
// pack_A: adjacency -> 128-bit masks, once per b (not per head).
// ---------------------------------------------------------------------------
__global__ __launch_bounds__(256) void pack_A(const float* __restrict__ A, uint* __restrict__ AW)
{
    const int b = blockIdx.x;
    const float4* Ab = (const float4*)(A + (size_t)b * 10000);
    for (int t = threadIdx.x; t < 400; t += 256) {
        const int row = t >> 2, word = t & 3;
        uint bits = 0;
        if (word < 3) {
            #pragma unroll
            for (int j = 0; j < 8; ++j) {
                float4 v = Ab[row * 25 + word * 8 + j];
                uint b4 = (v.x > 0.f ? 1u : 0u) | (v.y > 0.f ? 2u : 0u)
                        | (v.z > 0.f ? 4u : 0u) | (v.w > 0.f ? 8u : 0u);
                bits |= b4 << (j * 4);
            }
        } else {
            float4 v = Ab[row * 25 + 24];   // cols 96..99; 100..127 stay 0
            bits = (v.x > 0.f ? 1u : 0u) | (v.y > 0.f ? 2u : 0u)
                 | (v.z > 0.f ? 4u : 0u) | (v.w > 0.f ? 8u : 0u);
        }
        AW[(size_t)b * 400 + t] = bits;
    }
}

// ---------------------------------------------------------------------------
// Fused GAT layer v4 (bf16-plane dataflow): per (b, head) block, 512 thr.
//   F=65: reads fp32 X. F=128: reads hi/lo bf16 planes (zero conversion).
//   Always emits hi/lo bf16 planes (RNE hi + RNE residual).
//   In-register P feeding MFMA-2 directly; 3 barriers.
// ---------------------------------------------------------------------------
template<int F, int KD>
__global__ __launch_bounds__(512, 4) void gat_fused(
    const float*  __restrict__ xinF,   // [B][100][65] (F=65 only)
    const ushort* __restrict__ xinH,   // [B][12800] hi plane (F=128 only)
    const ushort* __restrict__ xinL,   // lo plane
    const uint*   __restrict__ AW,     // [B][100][4] packed adjacency
    const float*  __restrict__ W,      // [H][F][32]
    const float*  __restrict__ av,     // [H][64]
    ushort* __restrict__ outH,         // [B][12800] hi plane
    ushort* __restrict__ outL)         // lo plane
{
    extern __shared__ char smem[];
    char*  HTH = smem + OFF_HTH;
    char*  HTL = smem + OFF_HTL;
    char*  WTH = smem + OFF_WTH;
    char*  WTL = smem + OFF_WTL;
    uint*  ABu = (uint*)(smem + OFF_AB);
    float* ASV = (float*)(smem + OFF_ASV);
    float* ESV = (float*)(smem + OFF_ESV);
    float* EDV = (float*)(smem + OFF_EDV);
    float* INV = (float*)(smem + OFF_INV);

    const int tid = threadIdx.x;
    // XCD-grouped swizzle: 4 head-blocks of one b land on one XCD, adjacent slots
    const int task = (blockIdx.x & 7) * 512 + (blockIdx.x >> 3);
    const int b = task >> 2, hd = task & 3;
    const int w = tid >> 6, lane = tid & 63;
    const int c16 = lane & 15, r16 = lane >> 4;

    if (F == 65) {   // zero WT for k-padding (f 65..95)
        uint4 z = make_uint4(0, 0, 0, 0);
        #pragma unroll
        for (int i = 0; i < 2; ++i)
            *(uint4*)(smem + OFF_WTH + (i * 512 + tid) * 16) = z;
        __syncthreads();
    }

    // ---- prefetch x fragments before the staging barrier
    const int nA = (w * 16 + c16 < 100) ? (w * 16 + c16) : 99;
    uint4 xph[4], xpl[4];
    if (F == 128 && w < 7) {
        const ushort* xh = xinH + (size_t)b * 12800 + (size_t)nA * 128 + r16 * 8;
        const ushort* xl = xinL + (size_t)b * 12800 + (size_t)nA * 128 + r16 * 8;
        #pragma unroll
        for (int d = 0; d < 4; ++d) {
            xph[d] = *(const uint4*)(xh + d * 32);
            xpl[d] = *(const uint4*)(xl + d * 32);
        }
    }

    // ---- ph1: stage WT (RNE hi/lo, transposed), ASV, AB copy, tail zeroing
    {
        const float4* Wg4 = (const float4*)(W + (size_t)hd * F * 32);
        #pragma unroll
        for (int it = 0; it < 2; ++it) {
            int id = it * 512 + tid;            // F*8 chunks (f, o4)
            if (id < F * 8) {
                int f = id >> 3, o4 = (id & 7) * 4;
                float4 v = Wg4[id];
                ushort h0 = f2bf(v.x), l0 = f2bf(v.x - bf2f(h0));
                ushort h1 = f2bf(v.y), l1 = f2bf(v.y - bf2f(h1));
                ushort h2 = f2bf(v.z), l2 = f2bf(v.z - bf2f(h2));
                ushort h3 = f2bf(v.w), l3 = f2bf(v.w - bf2f(h3));
                *(ushort*)(WTH + swzb(o4 + 0, 2 * f)) = h0; *(ushort*)(WTL + swzb(o4 + 0, 2 * f)) = l0;
                *(ushort*)(WTH + swzb(o4 + 1, 2 * f)) = h1; *(ushort*)(WTL + swzb(o4 + 1, 2 * f)) = l1;
                *(ushort*)(WTH + swzb(o4 + 2, 2 * f)) = h2; *(ushort*)(WTL + swzb(o4 + 2, 2 * f)) = l2;
                *(ushort*)(WTH + swzb(o4 + 3, 2 * f)) = h3; *(ushort*)(WTL + swzb(o4 + 3, 2 * f)) = l3;
            }
        }
    }
    if (tid < 64) ASV[tid] = av[hd * 64 + tid];
    {
        const int idA = tid - 64;
        if (idA >= 0 && idA < 400) ABu[idA] = AW[(size_t)b * 400 + idA];
        else if (idA >= 400 && idA < 448) ABu[idA] = 0u;   // rows 100..111 -> mask 0
    }
    if (tid < 256) {    // zero hT cols 96..127 (96..99 rewritten in ph2)
        char* base = (tid & 128) ? HTL : HTH;
        const int rr = (tid >> 2) & 31, sl = 12 + (tid & 3);
        *(uint4*)(base + swzb(rr, sl * 16)) = make_uint4(0, 0, 0, 0);
    }
    if (tid < 28) { ESV[100 + tid] = 0.f; EDV[100 + tid] = 0.f; }
    __syncthreads();

    // ---- ph2: MFMA-1 h = x*W (wave w owns rows w*16..+15, both o-halves)
    if (w < 7) {
        f32x4 acc0 = {0.f, 0.f, 0.f, 0.f}, acc1 = {0.f, 0.f, 0.f, 0.f};
        #pragma unroll
        for (int d = 0; d < KD; ++d) {
            short8 ah, al;
            if (F == 128) {
                ah = u4s8(xph[d]);
                al = u4s8(xpl[d]);
            } else {
                const float* xg = xinF + (size_t)b * Nn * 65;
                const int f0 = d * 32 + r16 * 8;
                float xv[8];
                #pragma unroll
                for (int j = 0; j < 8; ++j) {
                    int f = f0 + j;
                    xv[j] = (f < 65) ? xg[(size_t)nA * 65 + f] : 0.f;
                }
                uint hu[4], lu[4];
                #pragma unroll
                for (int i = 0; i < 4; ++i) {
                    uint u0 = __float_as_uint(xv[2 * i]);
                    uint u1 = __float_as_uint(xv[2 * i + 1]);
                    float l0 = xv[2 * i]     - __uint_as_float(u0 & 0xFFFF0000u);
                    float l1 = xv[2 * i + 1] - __uint_as_float(u1 & 0xFFFF0000u);
                    hu[i] = __builtin_amdgcn_perm(u1, u0, 0x07060302u);
                    lu[i] = __builtin_amdgcn_perm(__float_as_uint(l1), __float_as_uint(l0), 0x07060302u);
                }
                ah = mk8(hu[0], hu[1], hu[2], hu[3]);
                al = mk8(lu[0], lu[1], lu[2], lu[3]);
            }
            const int kb = d * 64 + r16 * 16;
            short8 bh0 = *(const short8*)(WTH + swzb(c16, kb));
            short8 bl0 = *(const short8*)(WTL + swzb(c16, kb));
            short8 bh1 = *(const short8*)(WTH + swzb(16 + c16, kb));
            short8 bl1 = *(const short8*)(WTL + swzb(16 + c16, kb));
            acc0 = __builtin_amdgcn_mfma_f32_16x16x32_bf16(ah, bh0, acc0, 0, 0, 0);
            acc0 = __builtin_amdgcn_mfma_f32_16x16x32_bf16(al, bh0, acc0, 0, 0, 0);
            acc0 = __builtin_amdgcn_mfma_f32_16x16x32_bf16(ah, bl0, acc0, 0, 0, 0);
            acc1 = __builtin_amdgcn_mfma_f32_16x16x32_bf16(ah, bh1, acc1, 0, 0, 0);
            acc1 = __builtin_amdgcn_mfma_f32_16x16x32_bf16(al, bh1, acc1, 0, 0, 0);
            acc1 = __builtin_amdgcn_mfma_f32_16x16x32_bf16(ah, bl1, acc1, 0, 0, 0);
        }
        const int n0 = w * 16 + r16 * 4;
        if (n0 < 100) {   // hT split write: rows o, cols n0..n0+3 (all <100)
            ushort h0 = f2bf(acc0[0]), l0 = f2bf(acc0[0] - bf2f(h0));
            ushort h1 = f2bf(acc0[1]), l1 = f2bf(acc0[1] - bf2f(h1));
            ushort h2 = f2bf(acc0[2]), l2 = f2bf(acc0[2] - bf2f(h2));
            ushort h3 = f2bf(acc0[3]), l3 = f2bf(acc0[3] - bf2f(h3));
            uint2 uh; uh.x = (uint)h0 | ((uint)h1 << 16); uh.y = (uint)h2 | ((uint)h3 << 16);
            uint2 ul; ul.x = (uint)l0 | ((uint)l1 << 16); ul.y = (uint)l2 | ((uint)l3 << 16);
            *(uint2*)(HTH + swzb(c16, 2 * n0)) = uh;
            *(uint2*)(HTL + swzb(c16, 2 * n0)) = ul;
            h0 = f2bf(acc1[0]); l0 = f2bf(acc1[0] - bf2f(h0));
            h1 = f2bf(acc1[1]); l1 = f2bf(acc1[1] - bf2f(h1));
            h2 = f2bf(acc1[2]); l2 = f2bf(acc1[2] - bf2f(h2));
            h3 = f2bf(acc1[3]); l3 = f2bf(acc1[3] - bf2f(h3));
            uh.x = (uint)h0 | ((uint)h1 << 16); uh.y = (uint)h2 | ((uint)h3 << 16);
            ul.x = (uint)l0 | ((uint)l1 << 16); ul.y = (uint)l2 | ((uint)l3 << 16);
            *(uint2*)(HTH + swzb(16 + c16, 2 * n0)) = uh;
            *(uint2*)(HTL + swzb(16 + c16, 2 * n0)) = ul;
        }
        // es/ed: reduce acc*a over 32 o's (both halves pre-summed, 16-lane xor)
        const float as0 = ASV[c16], as1 = ASV[16 + c16];
        const float ad0 = ASV[32 + c16], ad1 = ASV[48 + c16];
        #pragma unroll
        for (int r = 0; r < 4; ++r) {
            float vs = acc0[r] * as0 + acc1[r] * as1;
            float vd = acc0[r] * ad0 + acc1[r] * ad1;
            #pragma unroll
            for (int mk = 1; mk <= 8; mk <<= 1) {
                vs += __shfl_xor(vs, mk, 64);
                vd += __shfl_xor(vd, mk, 64);
            }
            if (c16 == 0 && n0 + r < 100) { ESV[n0 + r] = vs; EDV[n0 + r] = vd; }
        }
    }
    __syncthreads();

    // ---- ph3a: in-register P, MFMA-2 accumulate; rowsum -> INV (LDS)
    f32x4 acc0 = {0.f, 0.f, 0.f, 0.f}, acc1 = {0.f, 0.f, 0.f, 0.f};
    if (w < 7) {
        const int np = w * 16 + c16;            // P-row this lane supplies (<=111)
        const float esn = ESV[np];
        const uint4 abv = *(const uint4*)(ABu + np * 4);
        float rowsum = 0.f;
        #pragma unroll
        for (int d = 0; d < 4; ++d) {
            const uint wrd = (d == 0) ? abv.x : (d == 1) ? abv.y : (d == 2) ? abv.z : abv.w;
            const float4 ea = *(const float4*)(EDV + d * 32 + r16 * 8);
            const float4 eb = *(const float4*)(EDV + d * 32 + r16 * 8 + 4);
            float p0, p1, p2, p3, p4, p5, p6, p7, e;
            e = esn + ea.x; e = e > 0.f ? e : 0.2f * e; p0 = ((wrd >> (r16 * 8 + 0)) & 1u) ? __expf(e) : 0.f;
            e = esn + ea.y; e = e > 0.f ? e : 0.2f * e; p1 = ((wrd >> (r16 * 8 + 1)) & 1u) ? __expf(e) : 0.f;
            e = esn + ea.z; e = e > 0.f ? e : 0.2f * e; p2 = ((wrd >> (r16 * 8 + 2)) & 1u) ? __expf(e) : 0.f;
            e = esn + ea.w; e = e > 0.f ? e : 0.2f * e; p3 = ((wrd >> (r16 * 8 + 3)) & 1u) ? __expf(e) : 0.f;
            e = esn + eb.x; e = e > 0.f ? e : 0.2f * e; p4 = ((wrd >> (r16 * 8 + 4)) & 1u) ? __expf(e) : 0.f;
            e = esn + eb.y; e = e > 0.f ? e : 0.2f * e; p5 = ((wrd >> (r16 * 8 + 5)) & 1u) ? __expf(e) : 0.f;
            e = esn + eb.z; e = e > 0.f ? e : 0.2f * e; p6 = ((wrd >> (r16 * 8 + 6)) & 1u) ? __expf(e) : 0.f;
            e = esn + eb.w; e = e > 0.f ? e : 0.2f * e; p7 = ((wrd >> (r16 * 8 + 7)) & 1u) ? __expf(e) : 0.f;
            rowsum += p0 + p1 + p2 + p3 + p4 + p5 + p6 + p7;
            ushort h0 = f2bf(p0), h1 = f2bf(p1), h2 = f2bf(p2), h3 = f2bf(p3);
            ushort h4 = f2bf(p4), h5 = f2bf(p5), h6 = f2bf(p6), h7 = f2bf(p7);
            ushort q0 = f2bf(p0 - bf2f(h0)), q1 = f2bf(p1 - bf2f(h1));
            ushort q2 = f2bf(p2 - bf2f(h2)), q3 = f2bf(p3 - bf2f(h3));
            ushort q4 = f2bf(p4 - bf2f(h4)), q5 = f2bf(p5 - bf2f(h5));
            ushort q6 = f2bf(p6 - bf2f(h6)), q7 = f2bf(p7 - bf2f(h7));
            short8 ph = mk8((uint)h0 | ((uint)h1 << 16), (uint)h2 | ((uint)h3 << 16),
                            (uint)h4 | ((uint)h5 << 16), (uint)h6 | ((uint)h7 << 16));
            short8 pl = mk8((uint)q0 | ((uint)q1 << 16), (uint)q2 | ((uint)q3 << 16),
                            (uint)q4 | ((uint)q5 << 16), (uint)q6 | ((uint)q7 << 16));
            const int kb = d * 64 + r16 * 16;
            short8 bh0 = *(const short8*)(HTH + swzb(c16, kb));
            short8 bl0 = *(const short8*)(HTL + swzb(c16, kb));
            short8 bh1 = *(const short8*)(HTH + swzb(16 + c16, kb));
            short8 bl1 = *(const short8*)(HTL + swzb(16 + c16, kb));
            acc0 = __builtin_amdgcn_mfma_f32_16x16x32_bf16(ph, bh0, acc0, 0, 0, 0);
            acc0 = __builtin_amdgcn_mfma_f32_16x16x32_bf16(ph, bl0, acc0, 0, 0, 0);
            acc0 = __builtin_amdgcn_mfma_f32_16x16x32_bf16(pl, bh0, acc0, 0, 0, 0);
            acc1 = __builtin_amdgcn_mfma_f32_16x16x32_bf16(ph, bh1, acc1, 0, 0, 0);
            acc1 = __builtin_amdgcn_mfma_f32_16x16x32_bf16(ph, bl1, acc1, 0, 0, 0);
            acc1 = __builtin_amdgcn_mfma_f32_16x16x32_bf16(pl, bh1, acc1, 0, 0, 0);
        }
        rowsum += __shfl_xor(rowsum, 16, 64);
        rowsum += __shfl_xor(rowsum, 32, 64);
        if (r16 == 0 && np < 100) INV[np] = 1.0f / rowsum;
    }
    __syncthreads();

    // ---- ph3b: epilogue elu(acc * inv) -> bf16 hi/lo planes
    if (w < 7) {
        const int n0 = w * 16 + r16 * 4;
        const size_t obase = (size_t)b * 12800 + hd * 32;
        #pragma unroll
        for (int r = 0; r < 4; ++r) {
            const int n = n0 + r;
            if (n < 100) {
                const float inv = INV[n];
                float v0 = acc0[r] * inv; v0 = v0 > 0.f ? v0 : expm1f(v0);
                float v1 = acc1[r] * inv; v1 = v1 > 0.f ? v1 : expm1f(v1);
                ushort h0 = f2bf(v0), l0 = f2bf(v0 - bf2f(h0));
                ushort h1 = f2bf(v1), l1 = f2bf(v1 - bf2f(h1));
                outH[obase + n * 128 + c16] = h0;
                outL[obase + n * 128 + c16] = l0;
                outH[obase + n * 128 + 16 + c16] = h1;
                outL[obase + n * 128 + 16 + c16] = l1;
            }
        }
    }
}

// ---------------------------------------------------------------------------
// GEMM1: A from bf16 hi/lo planes (pure-copy staging), B fp32 convert,
// 128x128 tile, BK=64, SK=8, 2-deep register prefetch. 512 blocks, 2/CU.
// ---------------------------------------------------------------------------
#define G1_LDS 73728
__device__ __forceinline__ int aofs(int r, int kb) { return r * 144 + kb; }
__device__ __forceinline__ int bofs(int n, int kb) { return n * 144 + (kb ^ (((n >> 3) & 1) << 4)); }

__global__ __launch_bounds__(512, 4) void gemm1_mfma(
    const ushort* __restrict__ AHg, const ushort* __restrict__ ALg,
    const float* __restrict__ Bg, float* __restrict__ part)
{
    extern __shared__ char sm[];
    char* AH = sm;             // [128][144]
    char* AL = sm + 18432;
    char* BH = sm + 36864;     // [128][144]
    char* BL = sm + 55296;

    const int tid = threadIdx.x;
    const int pb = blockIdx.x;
    const int task = (pb & 7) * 64 + (pb >> 3);
    const int mb = task & 7, g = task >> 3;
    const int nb = g & 7, z = g >> 3;
    const int m0 = mb * 128, n0 = nb * 128;
    const int k0 = z * 1600;

    const int w = tid >> 6, lane = tid & 63;
    const int wn = w & 3, wm = w >> 2;               // wave tile 64m x 32n
    const int c16 = lane & 15, r16 = lane >> 4;

    const int ra = tid >> 2, kq = tid & 3;           // A: row, 16-k quarter
    const int bn = tid >> 2, kq4 = tid & 3;          // B: col n, 16-k quarter

    const ushort* Ah0 = AHg + (size_t)(m0 + ra) * K1 + k0 + kq * 16;
    const ushort* Al0 = ALg + (size_t)(m0 + ra) * K1 + k0 + kq * 16;
    const float*  Bb0 = Bg + ((size_t)k0 + kq4 * 16) * N1 + n0 + bn;

    f32x4 acc[4][2];
    #pragma unroll
    for (int i = 0; i < 4; ++i)
        #pragma unroll
        for (int j = 0; j < 2; ++j) acc[i][j] = (f32x4){0.f, 0.f, 0.f, 0.f};

    uint4 aH[2][2], aL[2][2];
    float bR[2][16];
    // prologue: prefetch iters 0 and 1
    #pragma unroll
    for (int pf = 0; pf < 2; ++pf) {
        const int off = pf * 64;
        aH[pf][0] = *(const uint4*)(Ah0 + off);
        aH[pf][1] = *(const uint4*)(Ah0 + off + 8);
        aL[pf][0] = *(const uint4*)(Al0 + off);
        aL[pf][1] = *(const uint4*)(Al0 + off + 8);
        #pragma unroll
        for (int j = 0; j < 16; ++j) bR[pf][j] = Bb0[(size_t)(off + j) * N1];
    }

    for (int it = 0; it < 25; ++it) {
        const int cur = it & 1;
        __syncthreads();   // previous iter's MFMA reads done -> LDS writable
        {   // A staging: pure copy from planes (pair-packed bf16 already)
            const int ab = aofs(ra, kq * 32);   // aofs has no XOR: +16 is safe
            *(uint4*)(AH + ab)      = aH[cur][0];
            *(uint4*)(AH + ab + 16) = aH[cur][1];
            *(uint4*)(AL + ab)      = aL[cur][0];
            *(uint4*)(AL + ab + 16) = aL[cur][1];
        }
        {   // B staging: trunc split + perm pack
            uint hi[8], lo[8];
            #pragma unroll
            for (int i = 0; i < 8; ++i) {
                uint u0 = __float_as_uint(bR[cur][2 * i]);
                uint u1 = __float_as_uint(bR[cur][2 * i + 1]);
                float l0 = bR[cur][2 * i]     - __uint_as_float(u0 & 0xFFFF0000u);
                float l1 = bR[cur][2 * i + 1] - __uint_as_float(u1 & 0xFFFF0000u);
                hi[i] = __builtin_amdgcn_perm(u1, u0, 0x07060302u);
                lo[i] = __builtin_amdgcn_perm(__float_as_uint(l1), __float_as_uint(l0), 0x07060302u);
            }
            const int bb0 = bofs(bn, kq4 * 32);        // swizzle-aware per-16B
            const int bb1 = bofs(bn, kq4 * 32 + 16);
            *(uint4*)(BH + bb0) = make_uint4(hi[0], hi[1], hi[2], hi[3]);
            *(uint4*)(BH + bb1) = make_uint4(hi[4], hi[5], hi[6], hi[7]);
            *(uint4*)(BL + bb0) = make_uint4(lo[0], lo[1], lo[2], lo[3]);
            *(uint4*)(BL + bb1) = make_uint4(lo[4], lo[5], lo[6], lo[7]);
        }
        __syncthreads();   // LDS tile ready

        if (it < 23) {     // prefetch iter it+2 into the buffer just drained
            const int off = (it + 2) * 64;
            aH[cur][0] = *(const uint4*)(Ah0 + off);
            aH[cur][1] = *(const uint4*)(Ah0 + off + 8);
            aL[cur][0] = *(const uint4*)(Al0 + off);
            aL[cur][1] = *(const uint4*)(Al0 + off + 8);
            #pragma unroll
            for (int j = 0; j < 16; ++j) bR[cur][j] = Bb0[(size_t)(off + j) * N1];
        }

        #pragma unroll
        for (int ks = 0; ks < 2; ++ks) {
            const int kb = ks * 64 + r16 * 16;
            short8 bh[2], bl[2];
            #pragma unroll
            for (int nf = 0; nf < 2; ++nf) {
                const int nr = wn * 32 + nf * 16 + c16;
                bh[nf] = *(const short8*)(BH + bofs(nr, kb));
                bl[nf] = *(const short8*)(BL + bofs(nr, kb));
            }
            #pragma unroll
            for (int mf = 0; mf < 4; ++mf) {
                const int ar = wm * 64 + mf * 16 + c16;
                short8 ah = *(const short8*)(AH + aofs(ar, kb));
                short8 al = *(const short8*)(AL + aofs(ar, kb));
                #pragma unroll
                for (int nf = 0; nf < 2; ++nf) {
                    acc[mf][nf] = __builtin_amdgcn_mfma_f32_16x16x32_bf16(ah, bh[nf], acc[mf][nf], 0, 0, 0);
                    acc[mf][nf] = __builtin_amdgcn_mfma_f32_16x16x32_bf16(al, bh[nf], acc[mf][nf], 0, 0, 0);
                    acc[mf][nf] = __builtin_amdgcn_mfma_f32_16x16x32_bf16(ah, bl[nf], acc[mf][nf], 0, 0, 0);
                }
            }
        }
    }

    float* pz = part + (size_t)z * M1 * N1;
    #pragma unroll
    for (int mf = 0; mf < 4; ++mf) {
        const int m = m0 + wm * 64 + mf * 16 + r16 * 4;
        #pragma unroll
        for (int nf = 0; nf < 2; ++nf) {
            const int n = n0 + wn * 32 + nf * 16 + c16;
            #pragma unroll
            for (int r = 0; r < 4; ++r)
                pz[(size_t)(m + r) * N1 + n] = acc[mf][nf][r];
        }
    }
}

// Reduce split-K partials + bias + BN(eval) + ReLU
__global__ __launch_bounds__(256) void bn1_reduce(
    const float* __restrict__ part, const float* __restrict__ pb1,
    const float* __restrict__ g1, const float* __restrict__ be1,
    float* __restrict__ y1)
{
    const int idx = blockIdx.x * 256 + threadIdx.x;
    float s = 0.f;
    #pragma unroll
    for (int z = 0; z < SK; ++z) s += part[(size_t)z * M1 * N1 + idx];
    const int j = idx & (N1 - 1);
    s += pb1[j];
    const float rbn = 1.0f / sqrtf(1.0f + 1e-5f);
    s = g1[j] * s * rbn + be1[j];
    y1[idx] = fmaxf(s, 0.f);
}

// GEMM2 (1024x1024)x(1024x128) + bias + BN + ReLU -> d_out
__global__ __launch_bounds__(128) void gemm2_bn(
    const float* __restrict__ y1, const float* __restrict__ W2,
    const float* __restrict__ pb2, const float* __restrict__ g2,
    const float* __restrict__ be2, float* __restrict__ out)
{
    __shared__ __align__(16) float xr[1024];
    const int tid = threadIdx.x, m = blockIdx.x;
    for (int i = tid; i < 1024; i += 128) xr[i] = y1[(size_t)m * 1024 + i];
    __syncthreads();
    float acc = 0.f;
    #pragma unroll 8
    for (int k = 0; k < 1024; ++k) acc += xr[k] * W2[k * 128 + tid];
    acc += pb2[tid];
    const float rbn = 1.0f / sqrtf(1.0f + 1e-5f);
    acc = g2[tid] * acc * rbn + be2[tid];
    out[(size_t)m * 128 + tid] = fmaxf(acc, 0.f);
}

// ---------------------------------------------------------------------------
extern "C" void kernel_launch(void* const* d_in, const int* in_sizes, int n_in,
                              void* d_out, int out_size, void* d_ws, size_t ws_size,
                              hipStream_t stream)
{
    const float* X   = (const float*)d_in[0];
    const float* A   = (const float*)d_in[1];
    const float* W0  = (const float*)d_in[2];
    const float* a0  = (const float*)d_in[3];
    const float* Wl  = (const float*)d_in[4];
    const float* al  = (const float*)d_in[5];
    const float* pW1 = (const float*)d_in[6];
    const float* pb1 = (const float*)d_in[7];
    const float* g1  = (const float*)d_in[8];
    const float* be1 = (const float*)d_in[9];
    const float* pW2 = (const float*)d_in[10];
    const float* pb2 = (const float*)d_in[11];
    const float* g2  = (const float*)d_in[12];
    const float* be2 = (const float*)d_in[13];
    float* out = (float*)d_out;

    // ws: xa(52.4MB: hi|lo planes) | xb(52.4MB: hi|lo planes, reused as part) | y1(4.2MB, AW overlay)
    float* ws = (float*)d_ws;
    float* xa = ws;
    float* xb = xa + (size_t)Bb * Nn * Dd;
    float* y1 = xb + (size_t)Bb * Nn * Dd;
    float* part = xb;
    uint*  AW = (uint*)y1;          // packed adjacency, dead before bn1 writes y1
    ushort* xaH = (ushort*)xa; ushort* xaL = xaH + (size_t)Bb * 12800;
    ushort* xbH = (ushort*)xb; ushort* xbL = xbH + (size_t)Bb * 12800;

    (void)hipFuncSetAttribute(reinterpret_cast<const void*>(gat_fused<65, 3>),
                              hipFuncAttributeMaxDynamicSharedMemorySize, GAT_LDS);
    (void)hipFuncSetAttribute(reinterpret_cast<const void*>(gat_fused<128, 4>),
                              hipFuncAttributeMaxDynamicSharedMemorySize, GAT_LDS);
    (void)hipFuncSetAttribute(reinterpret_cast<const void*>(gemm1_mfma),
                              hipFuncAttributeMaxDynamicSharedMemorySize, G1_LDS);

    pack_A<<<dim3(Bb), 256, 0, stream>>>(A, AW);
    // L0: X fp32 -> xa planes
    gat_fused<65, 3><<<dim3(Bb * Hh), 512, GAT_LDS, stream>>>(
        X, nullptr, nullptr, AW, W0, a0, xaH, xaL);
    // L1..L4 ping-pong planes: xa->xb->xa->xb->xa
    const ushort *sH = xaH, *sL = xaL;
    ushort *dH = xbH, *dL = xbL;
    for (int l = 1; l < 5; ++l) {
        gat_fused<128, 4><<<dim3(Bb * Hh), 512, GAT_LDS, stream>>>(
            nullptr, sH, sL, AW,
            Wl + (size_t)(l - 1) * Hh * Dd * Oo, al + (size_t)(l - 1) * Hh * 2 * Oo, dH, dL);
        ushort* t;
        t = (ushort*)sH; sH = dH; dH = t;
        t = (ushort*)sL; sL = dL; dL = t;
    }
    // after 4 swaps final planes are xaH/xaL; xb free for partials
    gemm1_mfma<<<dim3(512), 512, G1_LDS, stream>>>(xaH, xaL, pW1, part);
    bn1_reduce<<<dim3((M1 * N1) / 256), 256, 0, stream>>>(part, pb1, g1, be1, y1);
    gemm2_bn<<<dim3(M1), 128, 0, stream>>>(y1, pW2, pb2, g2, be2, out);
}

// Round 12
// 525.473 us; speedup vs baseline: 1.2838x; 1.2838x over previous
//
#include <hip/hip_runtime.h>
#include <math.h>

typedef __attribute__((ext_vector_type(8))) short short8;   // 8 bf16 (4 VGPR) MFMA A/B frag
typedef __attribute__((ext_vector_type(4))) float f32x4;    // MFMA C/D frag
typedef __attribute__((ext_vector_type(4))) uint  uint4v;

constexpr int Bb = 1024, Nn = 100, Hh = 4, Oo = 32, Dd = 128;
constexpr int K1 = 12800, N1 = 1024, M1 = 1024, SK = 8;

// bf16 round-to-nearest-even helpers
__device__ __forceinline__ ushort f2bf(float f) {
    uint u = __float_as_uint(f);
    return (ushort)((u + 0x7FFFu + ((u >> 16) & 1u)) >> 16);
}
__device__ __forceinline__ float bf2f(ushort h) {
    return __uint_as_float(((uint)h) << 16);
}
__device__ __forceinline__ short8 mk8(uint a, uint b, uint c, uint d) {
    uint4v v = {a, b, c, d};
    return __builtin_bit_cast(short8, v);
}
__device__ __forceinline__ short8 u4s8(uint4 v) {
    uint4v t = {v.x, v.y, v.z, v.w};
    return __builtin_bit_cast(short8, t);
}
// swizzle within [rows][256B] LDS tiles: XOR 16B-slot bits with row&7
__device__ __forceinline__ int swzb(int row, int kb)  { return row * 256 + (kb ^ ((row & 7) << 4)); }

// GAT LDS layout (dynamic, 36352 B)
#define OFF_HTH 0        /* hT hi [32][256B] */
#define OFF_HTL 8192
#define OFF_WTH 16384    /* WT hi [32][256B] */
#define OFF_WTL 24576
#define OFF_AB  32768    /* adjacency bitmask [112][4 u32] (448 words, >=400 zeroed) */
#define OFF_ASV 34560    /* a-vector 64 f32 */
#define OFF_ESV 34816    /* e_src [128] f32 */
#define OFF_EDV 35328    /* e_dst [128] f32 */
#define OFF_INV 35840    /* 1/rowsum [128] f32 */
#define GAT_LDS 36352

// ---------------------------------------------------------------------------
// pack_A: adjacency -> 128-bit masks, once per b (not per head).
// ---------------------------------------------------------------------------
__global__ __launch_bounds__(256) void pack_A(const float* __restrict__ A, uint* __restrict__ AW)
{
    const int b = blockIdx.x;
    const float4* Ab = (const float4*)(A + (size_t)b * 10000);
    for (int t = threadIdx.x; t < 400; t += 256) {
        const int row = t >> 2, word = t & 3;
        uint bits = 0;
        if (word < 3) {
            #pragma unroll
            for (int j = 0; j < 8; ++j) {
                float4 v = Ab[row * 25 + word * 8 + j];
                uint b4 = (v.x > 0.f ? 1u : 0u) | (v.y > 0.f ? 2u : 0u)
                        | (v.z > 0.f ? 4u : 0u) | (v.w > 0.f ? 8u : 0u);
                bits |= b4 << (j * 4);
            }
        } else {
            float4 v = Ab[row * 25 + 24];   // cols 96..99; 100..127 stay 0
            bits = (v.x > 0.f ? 1u : 0u) | (v.y > 0.f ? 2u : 0u)
                 | (v.z > 0.f ? 4u : 0u) | (v.w > 0.f ? 8u : 0u);
        }
        AW[(size_t)b * 400 + t] = bits;
    }
}

// ---------------------------------------------------------------------------
// Fused GAT layer v4 (bf16-plane dataflow): unchanged from R11.
// ---------------------------------------------------------------------------
template<int F, int KD>
__global__ __launch_bounds__(512, 4) void gat_fused(
    const float*  __restrict__ xinF,   // [B][100][65] (F=65 only)
    const ushort* __restrict__ xinH,   // [B][12800] hi plane (F=128 only)
    const ushort* __restrict__ xinL,   // lo plane
    const uint*   __restrict__ AW,     // [B][100][4] packed adjacency
    const float*  __restrict__ W,      // [H][F][32]
    const float*  __restrict__ av,     // [H][64]
    ushort* __restrict__ outH,         // [B][12800] hi plane
    ushort* __restrict__ outL)         // lo plane
{
    extern __shared__ char smem[];
    char*  HTH = smem + OFF_HTH;
    char*  HTL = smem + OFF_HTL;
    char*  WTH = smem + OFF_WTH;
    char*  WTL = smem + OFF_WTL;
    uint*  ABu = (uint*)(smem + OFF_AB);
    float* ASV = (float*)(smem + OFF_ASV);
    float* ESV = (float*)(smem + OFF_ESV);
    float* EDV = (float*)(smem + OFF_EDV);
    float* INV = (float*)(smem + OFF_INV);

    const int tid = threadIdx.x;
    // XCD-grouped swizzle: 4 head-blocks of one b land on one XCD, adjacent slots
    const int task = (blockIdx.x & 7) * 512 + (blockIdx.x >> 3);
    const int b = task >> 2, hd = task & 3;
    const int w = tid >> 6, lane = tid & 63;
    const int c16 = lane & 15, r16 = lane >> 4;

    if (F == 65) {   // zero WT for k-padding (f 65..95)
        uint4 z = make_uint4(0, 0, 0, 0);
        #pragma unroll
        for (int i = 0; i < 2; ++i)
            *(uint4*)(smem + OFF_WTH + (i * 512 + tid) * 16) = z;
        __syncthreads();
    }

    // ---- prefetch x fragments before the staging barrier
    const int nA = (w * 16 + c16 < 100) ? (w * 16 + c16) : 99;
    uint4 xph[4], xpl[4];
    if (F == 128 && w < 7) {
        const ushort* xh = xinH + (size_t)b * 12800 + (size_t)nA * 128 + r16 * 8;
        const ushort* xl = xinL + (size_t)b * 12800 + (size_t)nA * 128 + r16 * 8;
        #pragma unroll
        for (int d = 0; d < 4; ++d) {
            xph[d] = *(const uint4*)(xh + d * 32);
            xpl[d] = *(const uint4*)(xl + d * 32);
        }
    }

    // ---- ph1: stage WT (RNE hi/lo, transposed), ASV, AB copy, tail zeroing
    {
        const float4* Wg4 = (const float4*)(W + (size_t)hd * F * 32);
        #pragma unroll
        for (int it = 0; it < 2; ++it) {
            int id = it * 512 + tid;            // F*8 chunks (f, o4)
            if (id < F * 8) {
                int f = id >> 3, o4 = (id & 7) * 4;
                float4 v = Wg4[id];
                ushort h0 = f2bf(v.x), l0 = f2bf(v.x - bf2f(h0));
                ushort h1 = f2bf(v.y), l1 = f2bf(v.y - bf2f(h1));
                ushort h2 = f2bf(v.z), l2 = f2bf(v.z - bf2f(h2));
                ushort h3 = f2bf(v.w), l3 = f2bf(v.w - bf2f(h3));
                *(ushort*)(WTH + swzb(o4 + 0, 2 * f)) = h0; *(ushort*)(WTL + swzb(o4 + 0, 2 * f)) = l0;
                *(ushort*)(WTH + swzb(o4 + 1, 2 * f)) = h1; *(ushort*)(WTL + swzb(o4 + 1, 2 * f)) = l1;
                *(ushort*)(WTH + swzb(o4 + 2, 2 * f)) = h2; *(ushort*)(WTL + swzb(o4 + 2, 2 * f)) = l2;
                *(ushort*)(WTH + swzb(o4 + 3, 2 * f)) = h3; *(ushort*)(WTL + swzb(o4 + 3, 2 * f)) = l3;
            }
        }
    }
    if (tid < 64) ASV[tid] = av[hd * 64 + tid];
    {
        const int idA = tid - 64;
        if (idA >= 0 && idA < 400) ABu[idA] = AW[(size_t)b * 400 + idA];
        else if (idA >= 400 && idA < 448) ABu[idA] = 0u;   // rows 100..111 -> mask 0
    }
    if (tid < 256) {    // zero hT cols 96..127 (96..99 rewritten in ph2)
        char* base = (tid & 128) ? HTL : HTH;
        const int rr = (tid >> 2) & 31, sl = 12 + (tid & 3);
        *(uint4*)(base + swzb(rr, sl * 16)) = make_uint4(0, 0, 0, 0);
    }
    if (tid < 28) { ESV[100 + tid] = 0.f; EDV[100 + tid] = 0.f; }
    __syncthreads();

    // ---- ph2: MFMA-1 h = x*W (wave w owns rows w*16..+15, both o-halves)
    if (w < 7) {
        f32x4 acc0 = {0.f, 0.f, 0.f, 0.f}, acc1 = {0.f, 0.f, 0.f, 0.f};
        #pragma unroll
        for (int d = 0; d < KD; ++d) {
            short8 ah, al;
            if (F == 128) {
                ah = u4s8(xph[d]);
                al = u4s8(xpl[d]);
            } else {
                const float* xg = xinF + (size_t)b * Nn * 65;
                const int f0 = d * 32 + r16 * 8;
                float xv[8];
                #pragma unroll
                for (int j = 0; j < 8; ++j) {
                    int f = f0 + j;
                    xv[j] = (f < 65) ? xg[(size_t)nA * 65 + f] : 0.f;
                }
                uint hu[4], lu[4];
                #pragma unroll
                for (int i = 0; i < 4; ++i) {
                    uint u0 = __float_as_uint(xv[2 * i]);
                    uint u1 = __float_as_uint(xv[2 * i + 1]);
                    float l0 = xv[2 * i]     - __uint_as_float(u0 & 0xFFFF0000u);
                    float l1 = xv[2 * i + 1] - __uint_as_float(u1 & 0xFFFF0000u);
                    hu[i] = __builtin_amdgcn_perm(u1, u0, 0x07060302u);
                    lu[i] = __builtin_amdgcn_perm(__float_as_uint(l1), __float_as_uint(l0), 0x07060302u);
                }
                ah = mk8(hu[0], hu[1], hu[2], hu[3]);
                al = mk8(lu[0], lu[1], lu[2], lu[3]);
            }
            const int kb = d * 64 + r16 * 16;
            short8 bh0 = *(const short8*)(WTH + swzb(c16, kb));
            short8 bl0 = *(const short8*)(WTL + swzb(c16, kb));
            short8 bh1 = *(const short8*)(WTH + swzb(16 + c16, kb));
            short8 bl1 = *(const short8*)(WTL + swzb(16 + c16, kb));
            acc0 = __builtin_amdgcn_mfma_f32_16x16x32_bf16(ah, bh0, acc0, 0, 0, 0);
            acc0 = __builtin_amdgcn_mfma_f32_16x16x32_bf16(al, bh0, acc0, 0, 0, 0);
            acc0 = __builtin_amdgcn_mfma_f32_16x16x32_bf16(ah, bl0, acc0, 0, 0, 0);
            acc1 = __builtin_amdgcn_mfma_f32_16x16x32_bf16(ah, bh1, acc1, 0, 0, 0);
            acc1 = __builtin_amdgcn_mfma_f32_16x16x32_bf16(al, bh1, acc1, 0, 0, 0);
            acc1 = __builtin_amdgcn_mfma_f32_16x16x32_bf16(ah, bl1, acc1, 0, 0, 0);
        }
        const int n0 = w * 16 + r16 * 4;
        if (n0 < 100) {   // hT split write: rows o, cols n0..n0+3 (all <100)
            ushort h0 = f2bf(acc0[0]), l0 = f2bf(acc0[0] - bf2f(h0));
            ushort h1 = f2bf(acc0[1]), l1 = f2bf(acc0[1] - bf2f(h1));
            ushort h2 = f2bf(acc0[2]), l2 = f2bf(acc0[2] - bf2f(h2));
            ushort h3 = f2bf(acc0[3]), l3 = f2bf(acc0[3] - bf2f(h3));
            uint2 uh; uh.x = (uint)h0 | ((uint)h1 << 16); uh.y = (uint)h2 | ((uint)h3 << 16);
            uint2 ul; ul.x = (uint)l0 | ((uint)l1 << 16); ul.y = (uint)l2 | ((uint)l3 << 16);
            *(uint2*)(HTH + swzb(c16, 2 * n0)) = uh;
            *(uint2*)(HTL + swzb(c16, 2 * n0)) = ul;
            h0 = f2bf(acc1[0]); l0 = f2bf(acc1[0] - bf2f(h0));
            h1 = f2bf(acc1[1]); l1 = f2bf(acc1[1] - bf2f(h1));
            h2 = f2bf(acc1[2]); l2 = f2bf(acc1[2] - bf2f(h2));
            h3 = f2bf(acc1[3]); l3 = f2bf(acc1[3] - bf2f(h3));
            uh.x = (uint)h0 | ((uint)h1 << 16); uh.y = (uint)h2 | ((uint)h3 << 16);
            ul.x = (uint)l0 | ((uint)l1 << 16); ul.y = (uint)l2 | ((uint)l3 << 16);
            *(uint2*)(HTH + swzb(16 + c16, 2 * n0)) = uh;
            *(uint2*)(HTL + swzb(16 + c16, 2 * n0)) = ul;
        }
        // es/ed: reduce acc*a over 32 o's (both halves pre-summed, 16-lane xor)
        const float as0 = ASV[c16], as1 = ASV[16 + c16];
        const float ad0 = ASV[32 + c16], ad1 = ASV[48 + c16];
        #pragma unroll
        for (int r = 0; r < 4; ++r) {
            float vs = acc0[r] * as0 + acc1[r] * as1;
            float vd = acc0[r] * ad0 + acc1[r] * ad1;
            #pragma unroll
            for (int mk = 1; mk <= 8; mk <<= 1) {
                vs += __shfl_xor(vs, mk, 64);
                vd += __shfl_xor(vd, mk, 64);
            }
            if (c16 == 0 && n0 + r < 100) { ESV[n0 + r] = vs; EDV[n0 + r] = vd; }
        }
    }
    __syncthreads();

    // ---- ph3a: in-register P, MFMA-2 accumulate; rowsum -> INV (LDS)
    f32x4 acc0 = {0.f, 0.f, 0.f, 0.f}, acc1 = {0.f, 0.f, 0.f, 0.f};
    if (w < 7) {
        const int np = w * 16 + c16;            // P-row this lane supplies (<=111)
        const float esn = ESV[np];
        const uint4 abv = *(const uint4*)(ABu + np * 4);
        float rowsum = 0.f;
        #pragma unroll
        for (int d = 0; d < 4; ++d) {
            const uint wrd = (d == 0) ? abv.x : (d == 1) ? abv.y : (d == 2) ? abv.z : abv.w;
            const float4 ea = *(const float4*)(EDV + d * 32 + r16 * 8);
            const float4 eb = *(const float4*)(EDV + d * 32 + r16 * 8 + 4);
            float p0, p1, p2, p3, p4, p5, p6, p7, e;
            e = esn + ea.x; e = e > 0.f ? e : 0.2f * e; p0 = ((wrd >> (r16 * 8 + 0)) & 1u) ? __expf(e) : 0.f;
            e = esn + ea.y; e = e > 0.f ? e : 0.2f * e; p1 = ((wrd >> (r16 * 8 + 1)) & 1u) ? __expf(e) : 0.f;
            e = esn + ea.z; e = e > 0.f ? e : 0.2f * e; p2 = ((wrd >> (r16 * 8 + 2)) & 1u) ? __expf(e) : 0.f;
            e = esn + ea.w; e = e > 0.f ? e : 0.2f * e; p3 = ((wrd >> (r16 * 8 + 3)) & 1u) ? __expf(e) : 0.f;
            e = esn + eb.x; e = e > 0.f ? e : 0.2f * e; p4 = ((wrd >> (r16 * 8 + 4)) & 1u) ? __expf(e) : 0.f;
            e = esn + eb.y; e = e > 0.f ? e : 0.2f * e; p5 = ((wrd >> (r16 * 8 + 5)) & 1u) ? __expf(e) : 0.f;
            e = esn + eb.z; e = e > 0.f ? e : 0.2f * e; p6 = ((wrd >> (r16 * 8 + 6)) & 1u) ? __expf(e) : 0.f;
            e = esn + eb.w; e = e > 0.f ? e : 0.2f * e; p7 = ((wrd >> (r16 * 8 + 7)) & 1u) ? __expf(e) : 0.f;
            rowsum += p0 + p1 + p2 + p3 + p4 + p5 + p6 + p7;
            ushort h0 = f2bf(p0), h1 = f2bf(p1), h2 = f2bf(p2), h3 = f2bf(p3);
            ushort h4 = f2bf(p4), h5 = f2bf(p5), h6 = f2bf(p6), h7 = f2bf(p7);
            ushort q0 = f2bf(p0 - bf2f(h0)), q1 = f2bf(p1 - bf2f(h1));
            ushort q2 = f2bf(p2 - bf2f(h2)), q3 = f2bf(p3 - bf2f(h3));
            ushort q4 = f2bf(p4 - bf2f(h4)), q5 = f2bf(p5 - bf2f(h5));
            ushort q6 = f2bf(p6 - bf2f(h6)), q7 = f2bf(p7 - bf2f(h7));
            short8 ph = mk8((uint)h0 | ((uint)h1 << 16), (uint)h2 | ((uint)h3 << 16),
                            (uint)h4 | ((uint)h5 << 16), (uint)h6 | ((uint)h7 << 16));
            short8 pl = mk8((uint)q0 | ((uint)q1 << 16), (uint)q2 | ((uint)q3 << 16),
                            (uint)q4 | ((uint)q5 << 16), (uint)q6 | ((uint)q7 << 16));
            const int kb = d * 64 + r16 * 16;
            short8 bh0 = *(const short8*)(HTH + swzb(c16, kb));
            short8 bl0 = *(const short8*)(HTL + swzb(c16, kb));
            short8 bh1 = *(const short8*)(HTH + swzb(16 + c16, kb));
            short8 bl1 = *(const short8*)(HTL + swzb(16 + c16, kb));
            acc0 = __builtin_amdgcn_mfma_f32_16x16x32_bf16(ph, bh0, acc0, 0, 0, 0);
            acc0 = __builtin_amdgcn_mfma_f32_16x16x32_bf16(ph, bl0, acc0, 0, 0, 0);
            acc0 = __builtin_amdgcn_mfma_f32_16x16x32_bf16(pl, bh0, acc0, 0, 0, 0);
            acc1 = __builtin_amdgcn_mfma_f32_16x16x32_bf16(ph, bh1, acc1, 0, 0, 0);
            acc1 = __builtin_amdgcn_mfma_f32_16x16x32_bf16(ph, bl1, acc1, 0, 0, 0);
            acc1 = __builtin_amdgcn_mfma_f32_16x16x32_bf16(pl, bh1, acc1, 0, 0, 0);
        }
        rowsum += __shfl_xor(rowsum, 16, 64);
        rowsum += __shfl_xor(rowsum, 32, 64);
        if (r16 == 0 && np < 100) INV[np] = 1.0f / rowsum;
    }
    __syncthreads();

    // ---- ph3b: epilogue elu(acc * inv) -> bf16 hi/lo planes
    if (w < 7) {
        const int n0 = w * 16 + r16 * 4;
        const size_t obase = (size_t)b * 12800 + hd * 32;
        #pragma unroll
        for (int r = 0; r < 4; ++r) {
            const int n = n0 + r;
            if (n < 100) {
                const float inv = INV[n];
                float v0 = acc0[r] * inv; v0 = v0 > 0.f ? v0 : expm1f(v0);
                float v1 = acc1[r] * inv; v1 = v1 > 0.f ? v1 : expm1f(v1);
                ushort h0 = f2bf(v0), l0 = f2bf(v0 - bf2f(h0));
                ushort h1 = f2bf(v1), l1 = f2bf(v1 - bf2f(h1));
                outH[obase + n * 128 + c16] = h0;
                outL[obase + n * 128 + c16] = l0;
                outH[obase + n * 128 + 16 + c16] = h1;
                outL[obase + n * 128 + 16 + c16] = l1;
            }
        }
    }
}

// ---------------------------------------------------------------------------
// GEMM1: A from bf16 hi/lo planes, 128x128 tile, BK=64, SK=8, 2-deep
// register prefetch via NAMED double buffers (rule #20: no runtime-indexed
// register arrays -> two statically-instantiated phases per loop trip).
// ---------------------------------------------------------------------------
#define G1_LDS 73728
__device__ __forceinline__ int aofs(int r, int kb) { return r * 144 + kb; }
__device__ __forceinline__ int bofs(int n, int kb) { return n * 144 + (kb ^ (((n >> 3) & 1) << 4)); }

__global__ __launch_bounds__(512, 4) void gemm1_mfma(
    const ushort* __restrict__ AHg, const ushort* __restrict__ ALg,
    const float* __restrict__ Bg, float* __restrict__ part)
{
    extern __shared__ char sm[];
    char* AH = sm;             // [128][144]
    char* AL = sm + 18432;
    char* BH = sm + 36864;     // [128][144]
    char* BL = sm + 55296;

    const int tid = threadIdx.x;
    const int pb = blockIdx.x;
    const int task = (pb & 7) * 64 + (pb >> 3);
    const int mb = task & 7, g = task >> 3;
    const int nb = g & 7, z = g >> 3;
    const int m0 = mb * 128, n0 = nb * 128;
    const int k0 = z * 1600;

    const int w = tid >> 6, lane = tid & 63;
    const int wn = w & 3, wm = w >> 2;               // wave tile 64m x 32n
    const int c16 = lane & 15, r16 = lane >> 4;

    const int ra = tid >> 2, kq = tid & 3;           // A: row, 16-k quarter
    const int bn = tid >> 2, kq4 = tid & 3;          // B: col n, 16-k quarter

    const ushort* Ah0 = AHg + (size_t)(m0 + ra) * K1 + k0 + kq * 16;
    const ushort* Al0 = ALg + (size_t)(m0 + ra) * K1 + k0 + kq * 16;
    const float*  Bb0 = Bg + ((size_t)k0 + kq4 * 16) * N1 + n0 + bn;

    f32x4 acc[4][2];
    #pragma unroll
    for (int i = 0; i < 4; ++i)
        #pragma unroll
        for (int j = 0; j < 2; ++j) acc[i][j] = (f32x4){0.f, 0.f, 0.f, 0.f};

    // named double buffers (all static indexing -> registers)
    uint4 aH0a, aH0b, aL0a, aL0b; float bR0[16];
    uint4 aH1a, aH1b, aL1a, aL1b; float bR1[16];

    auto prefetch = [&](uint4& ha, uint4& hb, uint4& la, uint4& lb,
                        float (&bR)[16], int it) {
        const int off = it * 64;
        ha = *(const uint4*)(Ah0 + off);
        hb = *(const uint4*)(Ah0 + off + 8);
        la = *(const uint4*)(Al0 + off);
        lb = *(const uint4*)(Al0 + off + 8);
        #pragma unroll
        for (int j = 0; j < 16; ++j) bR[j] = Bb0[(size_t)(off + j) * N1];
    };

    auto body = [&](uint4& ha, uint4& hb, uint4& la, uint4& lb,
                    float (&bR)[16], int pf_it) {
        __syncthreads();   // previous iter's MFMA reads done -> LDS writable
        {   // A staging: pure copy from plane regs
            const int ab = aofs(ra, kq * 32);   // aofs has no XOR: +16 safe
            *(uint4*)(AH + ab)      = ha;
            *(uint4*)(AH + ab + 16) = hb;
            *(uint4*)(AL + ab)      = la;
            *(uint4*)(AL + ab + 16) = lb;
        }
        {   // B staging: trunc split + perm pack
            uint hi[8], lo[8];
            #pragma unroll
            for (int i = 0; i < 8; ++i) {
                uint u0 = __float_as_uint(bR[2 * i]);
                uint u1 = __float_as_uint(bR[2 * i + 1]);
                float l0 = bR[2 * i]     - __uint_as_float(u0 & 0xFFFF0000u);
                float l1 = bR[2 * i + 1] - __uint_as_float(u1 & 0xFFFF0000u);
                hi[i] = __builtin_amdgcn_perm(u1, u0, 0x07060302u);
                lo[i] = __builtin_amdgcn_perm(__float_as_uint(l1), __float_as_uint(l0), 0x07060302u);
            }
            const int bb0 = bofs(bn, kq4 * 32);        // swizzle-aware per-16B
            const int bb1 = bofs(bn, kq4 * 32 + 16);
            *(uint4*)(BH + bb0) = make_uint4(hi[0], hi[1], hi[2], hi[3]);
            *(uint4*)(BH + bb1) = make_uint4(hi[4], hi[5], hi[6], hi[7]);
            *(uint4*)(BL + bb0) = make_uint4(lo[0], lo[1], lo[2], lo[3]);
            *(uint4*)(BL + bb1) = make_uint4(lo[4], lo[5], lo[6], lo[7]);
        }
        __syncthreads();   // LDS tile ready

        if (pf_it < 25) prefetch(ha, hb, la, lb, bR, pf_it);

        #pragma unroll
        for (int ks = 0; ks < 2; ++ks) {
            const int kb = ks * 64 + r16 * 16;
            short8 bh[2], bl[2];
            #pragma unroll
            for (int nf = 0; nf < 2; ++nf) {
                const int nr = wn * 32 + nf * 16 + c16;
                bh[nf] = *(const short8*)(BH + bofs(nr, kb));
                bl[nf] = *(const short8*)(BL + bofs(nr, kb));
            }
            #pragma unroll
            for (int mf = 0; mf < 4; ++mf) {
                const int ar = wm * 64 + mf * 16 + c16;
                short8 ah = *(const short8*)(AH + aofs(ar, kb));
                short8 al = *(const short8*)(AL + aofs(ar, kb));
                #pragma unroll
                for (int nf = 0; nf < 2; ++nf) {
                    acc[mf][nf] = __builtin_amdgcn_mfma_f32_16x16x32_bf16(ah, bh[nf], acc[mf][nf], 0, 0, 0);
                    acc[mf][nf] = __builtin_amdgcn_mfma_f32_16x16x32_bf16(al, bh[nf], acc[mf][nf], 0, 0, 0);
                    acc[mf][nf] = __builtin_amdgcn_mfma_f32_16x16x32_bf16(ah, bl[nf], acc[mf][nf], 0, 0, 0);
                }
            }
        }
    };

    // prologue: iters 0 and 1 into the two named buffers
    prefetch(aH0a, aH0b, aL0a, aL0b, bR0, 0);
    prefetch(aH1a, aH1b, aL1a, aL1b, bR1, 1);
    // 25 iterations, two statically-unrolled phases per trip
    for (int it = 0; it < 25; it += 2) {
        body(aH0a, aH0b, aL0a, aL0b, bR0, it + 2);
        if (it + 1 < 25)
            body(aH1a, aH1b, aL1a, aL1b, bR1, it + 3);
    }

    float* pz = part + (size_t)z * M1 * N1;
    #pragma unroll
    for (int mf = 0; mf < 4; ++mf) {
        const int m = m0 + wm * 64 + mf * 16 + r16 * 4;
        #pragma unroll
        for (int nf = 0; nf < 2; ++nf) {
            const int n = n0 + wn * 32 + nf * 16 + c16;
            #pragma unroll
            for (int r = 0; r < 4; ++r)
                pz[(size_t)(m + r) * N1 + n] = acc[mf][nf][r];
        }
    }
}

// Reduce split-K partials + bias + BN(eval) + ReLU
__global__ __launch_bounds__(256) void bn1_reduce(
    const float* __restrict__ part, const float* __restrict__ pb1,
    const float* __restrict__ g1, const float* __restrict__ be1,
    float* __restrict__ y1)
{
    const int idx = blockIdx.x * 256 + threadIdx.x;
    float s = 0.f;
    #pragma unroll
    for (int z = 0; z < SK; ++z) s += part[(size_t)z * M1 * N1 + idx];
    const int j = idx & (N1 - 1);
    s += pb1[j];
    const float rbn = 1.0f / sqrtf(1.0f + 1e-5f);
    s = g1[j] * s * rbn + be1[j];
    y1[idx] = fmaxf(s, 0.f);
}

// GEMM2 (1024x1024)x(1024x128) + bias + BN + ReLU -> d_out
__global__ __launch_bounds__(128) void gemm2_bn(
    const float* __restrict__ y1, const float* __restrict__ W2,
    const float* __restrict__ pb2, const float* __restrict__ g2,
    const float* __restrict__ be2, float* __restrict__ out)
{
    __shared__ __align__(16) float xr[1024];
    const int tid = threadIdx.x, m = blockIdx.x;
    for (int i = tid; i < 1024; i += 128) xr[i] = y1[(size_t)m * 1024 + i];
    __syncthreads();
    float acc = 0.f;
    #pragma unroll 8
    for (int k = 0; k < 1024; ++k) acc += xr[k] * W2[k * 128 + tid];
    acc += pb2[tid];
    const float rbn = 1.0f / sqrtf(1.0f + 1e-5f);
    acc = g2[tid] * acc * rbn + be2[tid];
    out[(size_t)m * 128 + tid] = fmaxf(acc, 0.f);
}

// ---------------------------------------------------------------------------
extern "C" void kernel_launch(void* const* d_in, const int* in_sizes, int n_in,
                              void* d_out, int out_size, void* d_ws, size_t ws_size,
                              hipStream_t stream)
{
    const float* X   = (const float*)d_in[0];
    const float* A   = (const float*)d_in[1];
    const float* W0  = (const float*)d_in[2];
    const float* a0  = (const float*)d_in[3];
    const float* Wl  = (const float*)d_in[4];
    const float* al  = (const float*)d_in[5];
    const float* pW1 = (const float*)d_in[6];
    const float* pb1 = (const float*)d_in[7];
    const float* g1  = (const float*)d_in[8];
    const float* be1 = (const float*)d_in[9];
    const float* pW2 = (const float*)d_in[10];
    const float* pb2 = (const float*)d_in[11];
    const float* g2  = (const float*)d_in[12];
    const float* be2 = (const float*)d_in[13];
    float* out = (float*)d_out;

    // ws: xa(52.4MB: hi|lo planes) | xb(52.4MB: hi|lo planes, reused as part) | y1(4.2MB, AW overlay)
    float* ws = (float*)d_ws;
    float* xa = ws;
    float* xb = xa + (size_t)Bb * Nn * Dd;
    float* y1 = xb + (size_t)Bb * Nn * Dd;
    float* part = xb;
    uint*  AW = (uint*)y1;          // packed adjacency, dead before bn1 writes y1
    ushort* xaH = (ushort*)xa; ushort* xaL = xaH + (size_t)Bb * 12800;
    ushort* xbH = (ushort*)xb; ushort* xbL = xbH + (size_t)Bb * 12800;

    (void)hipFuncSetAttribute(reinterpret_cast<const void*>(gat_fused<65, 3>),
                              hipFuncAttributeMaxDynamicSharedMemorySize, GAT_LDS);
    (void)hipFuncSetAttribute(reinterpret_cast<const void*>(gat_fused<128, 4>),
                              hipFuncAttributeMaxDynamicSharedMemorySize, GAT_LDS);
    (void)hipFuncSetAttribute(reinterpret_cast<const void*>(gemm1_mfma),
                              hipFuncAttributeMaxDynamicSharedMemorySize, G1_LDS);

    pack_A<<<dim3(Bb), 256, 0, stream>>>(A, AW);
    // L0: X fp32 -> xa planes
    gat_fused<65, 3><<<dim3(Bb * Hh), 512, GAT_LDS, stream>>>(
        X, nullptr, nullptr, AW, W0, a0, xaH, xaL);
    // L1..L4 ping-pong planes: xa->xb->xa->xb->xa
    const ushort *sH = xaH, *sL = xaL;
    ushort *dH = xbH, *dL = xbL;
    for (int l = 1; l < 5; ++l) {
        gat_fused<128, 4><<<dim3(Bb * Hh), 512, GAT_LDS, stream>>>(
            nullptr, sH, sL, AW,
            Wl + (size_t)(l - 1) * Hh * Dd * Oo, al + (size_t)(l - 1) * Hh * 2 * Oo, dH, dL);
        ushort* t;
        t = (ushort*)sH; sH = dH; dH = t;
        t = (ushort*)sL; sL = dL; dL = t;
    }
    // after 4 swaps final planes are xaH/xaL; xb free for partials
    gemm1_mfma<<<dim3(512), 512, G1_LDS, stream>>>(xaH, xaL, pW1, part);
    bn1_reduce<<<dim3((M1 * N1) / 256), 256, 0, stream>>>(part, pb1, g1, be1, y1);
    gemm2_bn<<<dim3(M1), 128, 0, stream>>>(y1, pW2, pb2, g2, be2, out);
}

// Round 13
// 495.357 us; speedup vs baseline: 1.3618x; 1.0608x over previous
//
#include <hip/hip_runtime.h>
#include <math.h>

typedef __attribute__((ext_vector_type(8))) short short8;   // 8 bf16 (4 VGPR) MFMA A/B frag
typedef __attribute__((ext_vector_type(4))) float f32x4;    // MFMA C/D frag
typedef __attribute__((ext_vector_type(4))) uint  uint4v;

constexpr int Bb = 1024, Nn = 100, Hh = 4, Oo = 32, Dd = 128;
constexpr int K1 = 12800, N1 = 1024, M1 = 1024, SK = 8;

// bf16 round-to-nearest-even helpers
__device__ __forceinline__ ushort f2bf(float f) {
    uint u = __float_as_uint(f);
    return (ushort)((u + 0x7FFFu + ((u >> 16) & 1u)) >> 16);
}
__device__ __forceinline__ float bf2f(ushort h) {
    return __uint_as_float(((uint)h) << 16);
}
__device__ __forceinline__ short8 mk8(uint a, uint b, uint c, uint d) {
    uint4v v = {a, b, c, d};
    return __builtin_bit_cast(short8, v);
}
__device__ __forceinline__ short8 u4s8(uint4 v) {
    uint4v t = {v.x, v.y, v.z, v.w};
    return __builtin_bit_cast(short8, t);
}
// swizzle within [rows][256B] LDS tiles: XOR 16B-slot bits with row&7
__device__ __forceinline__ int swzb(int row, int kb)  { return row * 256 + (kb ^ ((row & 7) << 4)); }

// GAT LDS layout (dynamic, 36352 B)
#define OFF_HTH 0        /* hT hi [32][256B] */
#define OFF_HTL 8192
#define OFF_WTH 16384    /* WT hi [32][256B] */
#define OFF_WTL 24576
#define OFF_AB  32768    /* adjacency bitmask [112][4 u32] (448 words, >=400 zeroed) */
#define OFF_ASV 34560    /* a-vector 64 f32 */
#define OFF_ESV 34816    /* e_src [128] f32 */
#define OFF_EDV 35328    /* e_dst [128] f32 */
#define OFF_INV 35840    /* 1/rowsum [128] f32 */
#define GAT_LDS 36352

// ---------------------------------------------------------------------------
// pack_A: adjacency -> 128-bit masks, once per b (not per head).
// ---------------------------------------------------------------------------
__global__ __launch_bounds__(256) void pack_A(const float* __restrict__ A, uint* __restrict__ AW)
{
    const int b = blockIdx.x;
    const float4* Ab = (const float4*)(A + (size_t)b * 10000);
    for (int t = threadIdx.x; t < 400; t += 256) {
        const int row = t >> 2, word = t & 3;
        uint bits = 0;
        if (word < 3) {
            #pragma unroll
            for (int j = 0; j < 8; ++j) {
                float4 v = Ab[row * 25 + word * 8 + j];
                uint b4 = (v.x > 0.f ? 1u : 0u) | (v.y > 0.f ? 2u : 0u)
                        | (v.z > 0.f ? 4u : 0u) | (v.w > 0.f ? 8u : 0u);
                bits |= b4 << (j * 4);
            }
        } else {
            float4 v = Ab[row * 25 + 24];   // cols 96..99; 100..127 stay 0
            bits = (v.x > 0.f ? 1u : 0u) | (v.y > 0.f ? 2u : 0u)
                 | (v.z > 0.f ? 4u : 0u) | (v.w > 0.f ? 8u : 0u);
        }
        AW[(size_t)b * 400 + t] = bits;
    }
}

// ---------------------------------------------------------------------------
// Fused GAT layer v4 (bf16-plane dataflow): unchanged from R11/R12.
// ---------------------------------------------------------------------------
template<int F, int KD>
__global__ __launch_bounds__(512, 4) void gat_fused(
    const float*  __restrict__ xinF,   // [B][100][65] (F=65 only)
    const ushort* __restrict__ xinH,   // [B][12800] hi plane (F=128 only)
    const ushort* __restrict__ xinL,   // lo plane
    const uint*   __restrict__ AW,     // [B][100][4] packed adjacency
    const float*  __restrict__ W,      // [H][F][32]
    const float*  __restrict__ av,     // [H][64]
    ushort* __restrict__ outH,         // [B][12800] hi plane
    ushort* __restrict__ outL)         // lo plane
{
    extern __shared__ char smem[];
    char*  HTH = smem + OFF_HTH;
    char*  HTL = smem + OFF_HTL;
    char*  WTH = smem + OFF_WTH;
    char*  WTL = smem + OFF_WTL;
    uint*  ABu = (uint*)(smem + OFF_AB);
    float* ASV = (float*)(smem + OFF_ASV);
    float* ESV = (float*)(smem + OFF_ESV);
    float* EDV = (float*)(smem + OFF_EDV);
    float* INV = (float*)(smem + OFF_INV);

    const int tid = threadIdx.x;
    // XCD-grouped swizzle: 4 head-blocks of one b land on one XCD, adjacent slots
    const int task = (blockIdx.x & 7) * 512 + (blockIdx.x >> 3);
    const int b = task >> 2, hd = task & 3;
    const int w = tid >> 6, lane = tid & 63;
    const int c16 = lane & 15, r16 = lane >> 4;

    if (F == 65) {   // zero WT for k-padding (f 65..95)
        uint4 z = make_uint4(0, 0, 0, 0);
        #pragma unroll
        for (int i = 0; i < 2; ++i)
            *(uint4*)(smem + OFF_WTH + (i * 512 + tid) * 16) = z;
        __syncthreads();
    }

    // ---- prefetch x fragments before the staging barrier
    const int nA = (w * 16 + c16 < 100) ? (w * 16 + c16) : 99;
    uint4 xph[4], xpl[4];
    if (F == 128 && w < 7) {
        const ushort* xh = xinH + (size_t)b * 12800 + (size_t)nA * 128 + r16 * 8;
        const ushort* xl = xinL + (size_t)b * 12800 + (size_t)nA * 128 + r16 * 8;
        #pragma unroll
        for (int d = 0; d < 4; ++d) {
            xph[d] = *(const uint4*)(xh + d * 32);
            xpl[d] = *(const uint4*)(xl + d * 32);
        }
    }

    // ---- ph1: stage WT (RNE hi/lo, transposed), ASV, AB copy, tail zeroing
    {
        const float4* Wg4 = (const float4*)(W + (size_t)hd * F * 32);
        #pragma unroll
        for (int it = 0; it < 2; ++it) {
            int id = it * 512 + tid;            // F*8 chunks (f, o4)
            if (id < F * 8) {
                int f = id >> 3, o4 = (id & 7) * 4;
                float4 v = Wg4[id];
                ushort h0 = f2bf(v.x), l0 = f2bf(v.x - bf2f(h0));
                ushort h1 = f2bf(v.y), l1 = f2bf(v.y - bf2f(h1));
                ushort h2 = f2bf(v.z), l2 = f2bf(v.z - bf2f(h2));
                ushort h3 = f2bf(v.w), l3 = f2bf(v.w - bf2f(h3));
                *(ushort*)(WTH + swzb(o4 + 0, 2 * f)) = h0; *(ushort*)(WTL + swzb(o4 + 0, 2 * f)) = l0;
                *(ushort*)(WTH + swzb(o4 + 1, 2 * f)) = h1; *(ushort*)(WTL + swzb(o4 + 1, 2 * f)) = l1;
                *(ushort*)(WTH + swzb(o4 + 2, 2 * f)) = h2; *(ushort*)(WTL + swzb(o4 + 2, 2 * f)) = l2;
                *(ushort*)(WTH + swzb(o4 + 3, 2 * f)) = h3; *(ushort*)(WTL + swzb(o4 + 3, 2 * f)) = l3;
            }
        }
    }
    if (tid < 64) ASV[tid] = av[hd * 64 + tid];
    {
        const int idA = tid - 64;
        if (idA >= 0 && idA < 400) ABu[idA] = AW[(size_t)b * 400 + idA];
        else if (idA >= 400 && idA < 448) ABu[idA] = 0u;   // rows 100..111 -> mask 0
    }
    if (tid < 256) {    // zero hT cols 96..127 (96..99 rewritten in ph2)
        char* base = (tid & 128) ? HTL : HTH;
        const int rr = (tid >> 2) & 31, sl = 12 + (tid & 3);
        *(uint4*)(base + swzb(rr, sl * 16)) = make_uint4(0, 0, 0, 0);
    }
    if (tid < 28) { ESV[100 + tid] = 0.f; EDV[100 + tid] = 0.f; }
    __syncthreads();

    // ---- ph2: MFMA-1 h = x*W (wave w owns rows w*16..+15, both o-halves)
    if (w < 7) {
        f32x4 acc0 = {0.f, 0.f, 0.f, 0.f}, acc1 = {0.f, 0.f, 0.f, 0.f};
        #pragma unroll
        for (int d = 0; d < KD; ++d) {
            short8 ah, al;
            if (F == 128) {
                ah = u4s8(xph[d]);
                al = u4s8(xpl[d]);
            } else {
                const float* xg = xinF + (size_t)b * Nn * 65;
                const int f0 = d * 32 + r16 * 8;
                float xv[8];
                #pragma unroll
                for (int j = 0; j < 8; ++j) {
                    int f = f0 + j;
                    xv[j] = (f < 65) ? xg[(size_t)nA * 65 + f] : 0.f;
                }
                uint hu[4], lu[4];
                #pragma unroll
                for (int i = 0; i < 4; ++i) {
                    uint u0 = __float_as_uint(xv[2 * i]);
                    uint u1 = __float_as_uint(xv[2 * i + 1]);
                    float l0 = xv[2 * i]     - __uint_as_float(u0 & 0xFFFF0000u);
                    float l1 = xv[2 * i + 1] - __uint_as_float(u1 & 0xFFFF0000u);
                    hu[i] = __builtin_amdgcn_perm(u1, u0, 0x07060302u);
                    lu[i] = __builtin_amdgcn_perm(__float_as_uint(l1), __float_as_uint(l0), 0x07060302u);
                }
                ah = mk8(hu[0], hu[1], hu[2], hu[3]);
                al = mk8(lu[0], lu[1], lu[2], lu[3]);
            }
            const int kb = d * 64 + r16 * 16;
            short8 bh0 = *(const short8*)(WTH + swzb(c16, kb));
            short8 bl0 = *(const short8*)(WTL + swzb(c16, kb));
            short8 bh1 = *(const short8*)(WTH + swzb(16 + c16, kb));
            short8 bl1 = *(const short8*)(WTL + swzb(16 + c16, kb));
            acc0 = __builtin_amdgcn_mfma_f32_16x16x32_bf16(ah, bh0, acc0, 0, 0, 0);
            acc0 = __builtin_amdgcn_mfma_f32_16x16x32_bf16(al, bh0, acc0, 0, 0, 0);
            acc0 = __builtin_amdgcn_mfma_f32_16x16x32_bf16(ah, bl0, acc0, 0, 0, 0);
            acc1 = __builtin_amdgcn_mfma_f32_16x16x32_bf16(ah, bh1, acc1, 0, 0, 0);
            acc1 = __builtin_amdgcn_mfma_f32_16x16x32_bf16(al, bh1, acc1, 0, 0, 0);
            acc1 = __builtin_amdgcn_mfma_f32_16x16x32_bf16(ah, bl1, acc1, 0, 0, 0);
        }
        const int n0 = w * 16 + r16 * 4;
        if (n0 < 100) {   // hT split write: rows o, cols n0..n0+3 (all <100)
            ushort h0 = f2bf(acc0[0]), l0 = f2bf(acc0[0] - bf2f(h0));
            ushort h1 = f2bf(acc0[1]), l1 = f2bf(acc0[1] - bf2f(h1));
            ushort h2 = f2bf(acc0[2]), l2 = f2bf(acc0[2] - bf2f(h2));
            ushort h3 = f2bf(acc0[3]), l3 = f2bf(acc0[3] - bf2f(h3));
            uint2 uh; uh.x = (uint)h0 | ((uint)h1 << 16); uh.y = (uint)h2 | ((uint)h3 << 16);
            uint2 ul; ul.x = (uint)l0 | ((uint)l1 << 16); ul.y = (uint)l2 | ((uint)l3 << 16);
            *(uint2*)(HTH + swzb(c16, 2 * n0)) = uh;
            *(uint2*)(HTL + swzb(c16, 2 * n0)) = ul;
            h0 = f2bf(acc1[0]); l0 = f2bf(acc1[0] - bf2f(h0));
            h1 = f2bf(acc1[1]); l1 = f2bf(acc1[1] - bf2f(h1));
            h2 = f2bf(acc1[2]); l2 = f2bf(acc1[2] - bf2f(h2));
            h3 = f2bf(acc1[3]); l3 = f2bf(acc1[3] - bf2f(h3));
            uh.x = (uint)h0 | ((uint)h1 << 16); uh.y = (uint)h2 | ((uint)h3 << 16);
            ul.x = (uint)l0 | ((uint)l1 << 16); ul.y = (uint)l2 | ((uint)l3 << 16);
            *(uint2*)(HTH + swzb(16 + c16, 2 * n0)) = uh;
            *(uint2*)(HTL + swzb(16 + c16, 2 * n0)) = ul;
        }
        // es/ed: reduce acc*a over 32 o's (both halves pre-summed, 16-lane xor)
        const float as0 = ASV[c16], as1 = ASV[16 + c16];
        const float ad0 = ASV[32 + c16], ad1 = ASV[48 + c16];
        #pragma unroll
        for (int r = 0; r < 4; ++r) {
            float vs = acc0[r] * as0 + acc1[r] * as1;
            float vd = acc0[r] * ad0 + acc1[r] * ad1;
            #pragma unroll
            for (int mk = 1; mk <= 8; mk <<= 1) {
                vs += __shfl_xor(vs, mk, 64);
                vd += __shfl_xor(vd, mk, 64);
            }
            if (c16 == 0 && n0 + r < 100) { ESV[n0 + r] = vs; EDV[n0 + r] = vd; }
        }
    }
    __syncthreads();

    // ---- ph3a: in-register P, MFMA-2 accumulate; rowsum -> INV (LDS)
    f32x4 acc0 = {0.f, 0.f, 0.f, 0.f}, acc1 = {0.f, 0.f, 0.f, 0.f};
    if (w < 7) {
        const int np = w * 16 + c16;            // P-row this lane supplies (<=111)
        const float esn = ESV[np];
        const uint4 abv = *(const uint4*)(ABu + np * 4);
        float rowsum = 0.f;
        #pragma unroll
        for (int d = 0; d < 4; ++d) {
            const uint wrd = (d == 0) ? abv.x : (d == 1) ? abv.y : (d == 2) ? abv.z : abv.w;
            const float4 ea = *(const float4*)(EDV + d * 32 + r16 * 8);
            const float4 eb = *(const float4*)(EDV + d * 32 + r16 * 8 + 4);
            float p0, p1, p2, p3, p4, p5, p6, p7, e;
            e = esn + ea.x; e = e > 0.f ? e : 0.2f * e; p0 = ((wrd >> (r16 * 8 + 0)) & 1u) ? __expf(e) : 0.f;
            e = esn + ea.y; e = e > 0.f ? e : 0.2f * e; p1 = ((wrd >> (r16 * 8 + 1)) & 1u) ? __expf(e) : 0.f;
            e = esn + ea.z; e = e > 0.f ? e : 0.2f * e; p2 = ((wrd >> (r16 * 8 + 2)) & 1u) ? __expf(e) : 0.f;
            e = esn + ea.w; e = e > 0.f ? e : 0.2f * e; p3 = ((wrd >> (r16 * 8 + 3)) & 1u) ? __expf(e) : 0.f;
            e = esn + eb.x; e = e > 0.f ? e : 0.2f * e; p4 = ((wrd >> (r16 * 8 + 4)) & 1u) ? __expf(e) : 0.f;
            e = esn + eb.y; e = e > 0.f ? e : 0.2f * e; p5 = ((wrd >> (r16 * 8 + 5)) & 1u) ? __expf(e) : 0.f;
            e = esn + eb.z; e = e > 0.f ? e : 0.2f * e; p6 = ((wrd >> (r16 * 8 + 6)) & 1u) ? __expf(e) : 0.f;
            e = esn + eb.w; e = e > 0.f ? e : 0.2f * e; p7 = ((wrd >> (r16 * 8 + 7)) & 1u) ? __expf(e) : 0.f;
            rowsum += p0 + p1 + p2 + p3 + p4 + p5 + p6 + p7;
            ushort h0 = f2bf(p0), h1 = f2bf(p1), h2 = f2bf(p2), h3 = f2bf(p3);
            ushort h4 = f2bf(p4), h5 = f2bf(p5), h6 = f2bf(p6), h7 = f2bf(p7);
            ushort q0 = f2bf(p0 - bf2f(h0)), q1 = f2bf(p1 - bf2f(h1));
            ushort q2 = f2bf(p2 - bf2f(h2)), q3 = f2bf(p3 - bf2f(h3));
            ushort q4 = f2bf(p4 - bf2f(h4)), q5 = f2bf(p5 - bf2f(h5));
            ushort q6 = f2bf(p6 - bf2f(h6)), q7 = f2bf(p7 - bf2f(h7));
            short8 ph = mk8((uint)h0 | ((uint)h1 << 16), (uint)h2 | ((uint)h3 << 16),
                            (uint)h4 | ((uint)h5 << 16), (uint)h6 | ((uint)h7 << 16));
            short8 pl = mk8((uint)q0 | ((uint)q1 << 16), (uint)q2 | ((uint)q3 << 16),
                            (uint)q4 | ((uint)q5 << 16), (uint)q6 | ((uint)q7 << 16));
            const int kb = d * 64 + r16 * 16;
            short8 bh0 = *(const short8*)(HTH + swzb(c16, kb));
            short8 bl0 = *(const short8*)(HTL + swzb(c16, kb));
            short8 bh1 = *(const short8*)(HTH + swzb(16 + c16, kb));
            short8 bl1 = *(const short8*)(HTL + swzb(16 + c16, kb));
            acc0 = __builtin_amdgcn_mfma_f32_16x16x32_bf16(ph, bh0, acc0, 0, 0, 0);
            acc0 = __builtin_amdgcn_mfma_f32_16x16x32_bf16(ph, bl0, acc0, 0, 0, 0);
            acc0 = __builtin_amdgcn_mfma_f32_16x16x32_bf16(pl, bh0, acc0, 0, 0, 0);
            acc1 = __builtin_amdgcn_mfma_f32_16x16x32_bf16(ph, bh1, acc1, 0, 0, 0);
            acc1 = __builtin_amdgcn_mfma_f32_16x16x32_bf16(ph, bl1, acc1, 0, 0, 0);
            acc1 = __builtin_amdgcn_mfma_f32_16x16x32_bf16(pl, bh1, acc1, 0, 0, 0);
        }
        rowsum += __shfl_xor(rowsum, 16, 64);
        rowsum += __shfl_xor(rowsum, 32, 64);
        if (r16 == 0 && np < 100) INV[np] = 1.0f / rowsum;
    }
    __syncthreads();

    // ---- ph3b: epilogue elu(acc * inv) -> bf16 hi/lo planes
    if (w < 7) {
        const int n0 = w * 16 + r16 * 4;
        const size_t obase = (size_t)b * 12800 + hd * 32;
        #pragma unroll
        for (int r = 0; r < 4; ++r) {
            const int n = n0 + r;
            if (n < 100) {
                const float inv = INV[n];
                float v0 = acc0[r] * inv; v0 = v0 > 0.f ? v0 : expm1f(v0);
                float v1 = acc1[r] * inv; v1 = v1 > 0.f ? v1 : expm1f(v1);
                ushort h0 = f2bf(v0), l0 = f2bf(v0 - bf2f(h0));
                ushort h1 = f2bf(v1), l1 = f2bf(v1 - bf2f(h1));
                outH[obase + n * 128 + c16] = h0;
                outL[obase + n * 128 + c16] = l0;
                outH[obase + n * 128 + 16 + c16] = h1;
                outL[obase + n * 128 + 16 + c16] = l1;
            }
        }
    }
}

// ---------------------------------------------------------------------------
// GEMM1: A from bf16 hi/lo planes (pure-copy staging), B fp32 convert,
// 128x128 tile, BK=64, SK=8. R10-proven 1-deep in-place prefetch (no spill).
// ---------------------------------------------------------------------------
#define G1_LDS 73728
__device__ __forceinline__ int aofs(int r, int kb) { return r * 144 + kb; }
__device__ __forceinline__ int bofs(int n, int kb) { return n * 144 + (kb ^ (((n >> 3) & 1) << 4)); }

__global__ __launch_bounds__(512, 4) void gemm1_mfma(
    const ushort* __restrict__ AHg, const ushort* __restrict__ ALg,
    const float* __restrict__ Bg, float* __restrict__ part)
{
    extern __shared__ char sm[];
    char* AH = sm;             // [128][144]
    char* AL = sm + 18432;
    char* BH = sm + 36864;     // [128][144]
    char* BL = sm + 55296;

    const int tid = threadIdx.x;
    const int pb = blockIdx.x;
    const int task = (pb & 7) * 64 + (pb >> 3);
    const int mb = task & 7, g = task >> 3;
    const int nb = g & 7, z = g >> 3;
    const int m0 = mb * 128, n0 = nb * 128;
    const int k0 = z * 1600;

    const int w = tid >> 6, lane = tid & 63;
    const int wn = w & 3, wm = w >> 2;               // wave tile 64m x 32n
    const int c16 = lane & 15, r16 = lane >> 4;

    const int ra = tid >> 2, kq = tid & 3;           // A: row, 16-k quarter
    const int bn = tid >> 2, kq4 = tid & 3;          // B: col n, 16-k quarter

    const ushort* Ah0 = AHg + (size_t)(m0 + ra) * K1 + k0 + kq * 16;
    const ushort* Al0 = ALg + (size_t)(m0 + ra) * K1 + k0 + kq * 16;
    const float*  Bb0 = Bg + ((size_t)k0 + kq4 * 16) * N1 + n0 + bn;

    f32x4 acc[4][2];
    #pragma unroll
    for (int i = 0; i < 4; ++i)
        #pragma unroll
        for (int j = 0; j < 2; ++j) acc[i][j] = (f32x4){0.f, 0.f, 0.f, 0.f};

    // 1-deep prefetch registers (static names, reloaded in place)
    uint4 aha, ahb, ala, alb;
    float bR[16];
    aha = *(const uint4*)(Ah0);
    ahb = *(const uint4*)(Ah0 + 8);
    ala = *(const uint4*)(Al0);
    alb = *(const uint4*)(Al0 + 8);
    #pragma unroll
    for (int j = 0; j < 16; ++j) bR[j] = Bb0[(size_t)j * N1];

    for (int it = 0; it < 25; ++it) {
        __syncthreads();   // previous iter's MFMA reads done -> LDS writable
        {   // A staging: pure copy from plane regs
            const int ab = aofs(ra, kq * 32);   // aofs has no XOR: +16 safe
            *(uint4*)(AH + ab)      = aha;
            *(uint4*)(AH + ab + 16) = ahb;
            *(uint4*)(AL + ab)      = ala;
            *(uint4*)(AL + ab + 16) = alb;
        }
        {   // B staging: trunc split + perm pack
            uint hi[8], lo[8];
            #pragma unroll
            for (int i = 0; i < 8; ++i) {
                uint u0 = __float_as_uint(bR[2 * i]);
                uint u1 = __float_as_uint(bR[2 * i + 1]);
                float l0 = bR[2 * i]     - __uint_as_float(u0 & 0xFFFF0000u);
                float l1 = bR[2 * i + 1] - __uint_as_float(u1 & 0xFFFF0000u);
                hi[i] = __builtin_amdgcn_perm(u1, u0, 0x07060302u);
                lo[i] = __builtin_amdgcn_perm(__float_as_uint(l1), __float_as_uint(l0), 0x07060302u);
            }
            const int bb0 = bofs(bn, kq4 * 32);        // swizzle-aware per-16B
            const int bb1 = bofs(bn, kq4 * 32 + 16);
            *(uint4*)(BH + bb0) = make_uint4(hi[0], hi[1], hi[2], hi[3]);
            *(uint4*)(BH + bb1) = make_uint4(hi[4], hi[5], hi[6], hi[7]);
            *(uint4*)(BL + bb0) = make_uint4(lo[0], lo[1], lo[2], lo[3]);
            *(uint4*)(BL + bb1) = make_uint4(lo[4], lo[5], lo[6], lo[7]);
        }
        __syncthreads();   // LDS tile ready

        if (it < 24) {     // prefetch next iter into the same regs
            const int off = (it + 1) * 64;
            aha = *(const uint4*)(Ah0 + off);
            ahb = *(const uint4*)(Ah0 + off + 8);
            ala = *(const uint4*)(Al0 + off);
            alb = *(const uint4*)(Al0 + off + 8);
            #pragma unroll
            for (int j = 0; j < 16; ++j) bR[j] = Bb0[(size_t)(off + j) * N1];
        }

        #pragma unroll
        for (int ks = 0; ks < 2; ++ks) {
            const int kb = ks * 64 + r16 * 16;
            short8 bh[2], bl[2];
            #pragma unroll
            for (int nf = 0; nf < 2; ++nf) {
                const int nr = wn * 32 + nf * 16 + c16;
                bh[nf] = *(const short8*)(BH + bofs(nr, kb));
                bl[nf] = *(const short8*)(BL + bofs(nr, kb));
            }
            #pragma unroll
            for (int mf = 0; mf < 4; ++mf) {
                const int ar = wm * 64 + mf * 16 + c16;
                short8 ah = *(const short8*)(AH + aofs(ar, kb));
                short8 al = *(const short8*)(AL + aofs(ar, kb));
                #pragma unroll
                for (int nf = 0; nf < 2; ++nf) {
                    acc[mf][nf] = __builtin_amdgcn_mfma_f32_16x16x32_bf16(ah, bh[nf], acc[mf][nf], 0, 0, 0);
                    acc[mf][nf] = __builtin_amdgcn_mfma_f32_16x16x32_bf16(al, bh[nf], acc[mf][nf], 0, 0, 0);
                    acc[mf][nf] = __builtin_amdgcn_mfma_f32_16x16x32_bf16(ah, bl[nf], acc[mf][nf], 0, 0, 0);
                }
            }
        }
    }

    float* pz = part + (size_t)z * M1 * N1;
    #pragma unroll
    for (int mf = 0; mf < 4; ++mf) {
        const int m = m0 + wm * 64 + mf * 16 + r16 * 4;
        #pragma unroll
        for (int nf = 0; nf < 2; ++nf) {
            const int n = n0 + wn * 32 + nf * 16 + c16;
            #pragma unroll
            for (int r = 0; r < 4; ++r)
                pz[(size_t)(m + r) * N1 + n] = acc[mf][nf][r];
        }
    }
}

// Reduce split-K partials + bias + BN(eval) + ReLU
__global__ __launch_bounds__(256) void bn1_reduce(
    const float* __restrict__ part, const float* __restrict__ pb1,
    const float* __restrict__ g1, const float* __restrict__ be1,
    float* __restrict__ y1)
{
    const int idx = blockIdx.x * 256 + threadIdx.x;
    float s = 0.f;
    #pragma unroll
    for (int z = 0; z < SK; ++z) s += part[(size_t)z * M1 * N1 + idx];
    const int j = idx & (N1 - 1);
    s += pb1[j];
    const float rbn = 1.0f / sqrtf(1.0f + 1e-5f);
    s = g1[j] * s * rbn + be1[j];
    y1[idx] = fmaxf(s, 0.f);
}

// GEMM2 (1024x1024)x(1024x128) + bias + BN + ReLU -> d_out
__global__ __launch_bounds__(128) void gemm2_bn(
    const float* __restrict__ y1, const float* __restrict__ W2,
    const float* __restrict__ pb2, const float* __restrict__ g2,
    const float* __restrict__ be2, float* __restrict__ out)
{
    __shared__ __align__(16) float xr[1024];
    const int tid = threadIdx.x, m = blockIdx.x;
    for (int i = tid; i < 1024; i += 128) xr[i] = y1[(size_t)m * 1024 + i];
    __syncthreads();
    float acc = 0.f;
    #pragma unroll 8
    for (int k = 0; k < 1024; ++k) acc += xr[k] * W2[k * 128 + tid];
    acc += pb2[tid];
    const float rbn = 1.0f / sqrtf(1.0f + 1e-5f);
    acc = g2[tid] * acc * rbn + be2[tid];
    out[(size_t)m * 128 + tid] = fmaxf(acc, 0.f);
}

// ---------------------------------------------------------------------------
extern "C" void kernel_launch(void* const* d_in, const int* in_sizes, int n_in,
                              void* d_out, int out_size, void* d_ws, size_t ws_size,
                              hipStream_t stream)
{
    const float* X   = (const float*)d_in[0];
    const float* A   = (const float*)d_in[1];
    const float* W0  = (const float*)d_in[2];
    const float* a0  = (const float*)d_in[3];
    const float* Wl  = (const float*)d_in[4];
    const float* al  = (const float*)d_in[5];
    const float* pW1 = (const float*)d_in[6];
    const float* pb1 = (const float*)d_in[7];
    const float* g1  = (const float*)d_in[8];
    const float* be1 = (const float*)d_in[9];
    const float* pW2 = (const float*)d_in[10];
    const float* pb2 = (const float*)d_in[11];
    const float* g2  = (const float*)d_in[12];
    const float* be2 = (const float*)d_in[13];
    float* out = (float*)d_out;

    // ws: xa(52.4MB: hi|lo planes) | xb(52.4MB: hi|lo planes, reused as part) | y1(4.2MB, AW overlay)
    float* ws = (float*)d_ws;
    float* xa = ws;
    float* xb = xa + (size_t)Bb * Nn * Dd;
    float* y1 = xb + (size_t)Bb * Nn * Dd;
    float* part = xb;
    uint*  AW = (uint*)y1;          // packed adjacency, dead before bn1 writes y1
    ushort* xaH = (ushort*)xa; ushort* xaL = xaH + (size_t)Bb * 12800;
    ushort* xbH = (ushort*)xb; ushort* xbL = xbH + (size_t)Bb * 12800;

    (void)hipFuncSetAttribute(reinterpret_cast<const void*>(gat_fused<65, 3>),
                              hipFuncAttributeMaxDynamicSharedMemorySize, GAT_LDS);
    (void)hipFuncSetAttribute(reinterpret_cast<const void*>(gat_fused<128, 4>),
                              hipFuncAttributeMaxDynamicSharedMemorySize, GAT_LDS);
    (void)hipFuncSetAttribute(reinterpret_cast<const void*>(gemm1_mfma),
                              hipFuncAttributeMaxDynamicSharedMemorySize, G1_LDS);

    pack_A<<<dim3(Bb), 256, 0, stream>>>(A, AW);
    // L0: X fp32 -> xa planes
    gat_fused<65, 3><<<dim3(Bb * Hh), 512, GAT_LDS, stream>>>(
        X, nullptr, nullptr, AW, W0, a0, xaH, xaL);
    // L1..L4 ping-pong planes: xa->xb->xa->xb->xa
    const ushort *sH = xaH, *sL = xaL;
    ushort *dH = xbH, *dL = xbL;
    for (int l = 1; l < 5; ++l) {
        gat_fused<128, 4><<<dim3(Bb * Hh), 512, GAT_LDS, stream>>>(
            nullptr, sH, sL, AW,
            Wl + (size_t)(l - 1) * Hh * Dd * Oo, al + (size_t)(l - 1) * Hh * 2 * Oo, dH, dL);
        ushort* t;
        t = (ushort*)sH; sH = dH; dH = t;
        t = (ushort*)sL; sL = dL; dL = t;
    }
    // after 4 swaps final planes are xaH/xaL; xb free for partials
    gemm1_mfma<<<dim3(512), 512, G1_LDS, stream>>>(xaH, xaL, pW1, part);
    bn1_reduce<<<dim3((M1 * N1) / 256), 256, 0, stream>>>(part, pb1, g1, be1, y1);
    gemm2_bn<<<dim3(M1), 128, 0, stream>>>(y1, pW2, pb2, g2, be2, out);
}

// Round 14
// 493.250 us; speedup vs baseline: 1.3676x; 1.0043x over previous
//
#include <hip/hip_runtime.h>
#include <math.h>

typedef __attribute__((ext_vector_type(8))) short short8;   // 8 bf16 (4 VGPR) MFMA A/B frag
typedef __attribute__((ext_vector_type(4))) float f32x4;    // MFMA C/D frag
typedef __attribute__((ext_vector_type(4))) uint  uint4v;

constexpr int Bb = 1024, Nn = 100, Hh = 4, Oo = 32, Dd = 128;
constexpr int K1 = 12800, N1 = 1024, M1 = 1024, SK = 8;

#define SEL_H 0x05040100u   /* perm sel: low ushorts of (b,a) -> packed hi-pair */
#define SEL_L 0x07060302u   /* perm sel: high ushorts of (b,a) -> packed lo-pair */

// bf16 round-to-nearest-even helpers
__device__ __forceinline__ ushort f2bf(float f) {
    uint u = __float_as_uint(f);
    return (ushort)((u + 0x7FFFu + ((u >> 16) & 1u)) >> 16);
}
__device__ __forceinline__ float bf2f(ushort h) {
    return __uint_as_float(((uint)h) << 16);
}
__device__ __forceinline__ short8 mk8(uint a, uint b, uint c, uint d) {
    uint4v v = {a, b, c, d};
    return __builtin_bit_cast(short8, v);
}
// swizzle within [rows][256B] LDS tiles: XOR 16B-slot bits with row&7
__device__ __forceinline__ int swzb(int row, int kb)  { return row * 256 + (kb ^ ((row & 7) << 4)); }

// GAT LDS layout (dynamic, 36352 B)
#define OFF_HTH 0        /* hT hi [32][256B] */
#define OFF_HTL 8192
#define OFF_WTH 16384    /* WT hi [32][256B] */
#define OFF_WTL 24576
#define OFF_AB  32768    /* adjacency bitmask [112][4 u32] (448 words, >=400 zeroed) */
#define OFF_ASV 34560    /* a-vector 64 f32 */
#define OFF_ESV 34816    /* e_src [128] f32 */
#define OFF_EDV 35328    /* e_dst [128] f32 */
#define OFF_INV 35840    /* 1/rowsum [128] f32 */
#define GAT_LDS 36352

// ---------------------------------------------------------------------------
// pack_A: adjacency -> 128-bit masks, once per b (not per head).
// ---------------------------------------------------------------------------
__global__ __launch_bounds__(256) void pack_A(const float* __restrict__ A, uint* __restrict__ AW)
{
    const int b = blockIdx.x;
    const float4* Ab = (const float4*)(A + (size_t)b * 10000);
    for (int t = threadIdx.x; t < 400; t += 256) {
        const int row = t >> 2, word = t & 3;
        uint bits = 0;
        if (word < 3) {
            #pragma unroll
            for (int j = 0; j < 8; ++j) {
                float4 v = Ab[row * 25 + word * 8 + j];
                uint b4 = (v.x > 0.f ? 1u : 0u) | (v.y > 0.f ? 2u : 0u)
                        | (v.z > 0.f ? 4u : 0u) | (v.w > 0.f ? 8u : 0u);
                bits |= b4 << (j * 4);
            }
        } else {
            float4 v = Ab[row * 25 + 24];   // cols 96..99; 100..127 stay 0
            bits = (v.x > 0.f ? 1u : 0u) | (v.y > 0.f ? 2u : 0u)
                 | (v.z > 0.f ? 4u : 0u) | (v.w > 0.f ? 8u : 0u);
        }
        AW[(size_t)b * 400 + t] = bits;
    }
}

// ---------------------------------------------------------------------------
// Fused GAT layer v5 (PACKED bf16 plane dataflow: u32 = hi | lo<<16):
//   F=65 reads fp32 X; F=128 reads packed plane (1 perm per word to unpack).
//   Output: 8x u32 stores per thread (R10 store count, half its bytes read
//   downstream as conversion-free fragments).
// ---------------------------------------------------------------------------
template<int F, int KD>
__global__ __launch_bounds__(512, 4) void gat_fused(
    const float* __restrict__ xinF,   // [B][100][65] (F=65 only)
    const uint*  __restrict__ xinP,   // [B][12800] packed plane (F=128 only)
    const uint*  __restrict__ AW,     // [B][100][4] packed adjacency
    const float* __restrict__ W,      // [H][F][32]
    const float* __restrict__ av,     // [H][64]
    uint* __restrict__ outP)          // [B][12800] packed plane
{
    extern __shared__ char smem[];
    char*  HTH = smem + OFF_HTH;
    char*  HTL = smem + OFF_HTL;
    char*  WTH = smem + OFF_WTH;
    char*  WTL = smem + OFF_WTL;
    uint*  ABu = (uint*)(smem + OFF_AB);
    float* ASV = (float*)(smem + OFF_ASV);
    float* ESV = (float*)(smem + OFF_ESV);
    float* EDV = (float*)(smem + OFF_EDV);
    float* INV = (float*)(smem + OFF_INV);

    const int tid = threadIdx.x;
    // XCD-grouped swizzle: 4 head-blocks of one b land on one XCD, adjacent slots
    const int task = (blockIdx.x & 7) * 512 + (blockIdx.x >> 3);
    const int b = task >> 2, hd = task & 3;
    const int w = tid >> 6, lane = tid & 63;
    const int c16 = lane & 15, r16 = lane >> 4;

    if (F == 65) {   // zero WT for k-padding (f 65..95)
        uint4 z = make_uint4(0, 0, 0, 0);
        #pragma unroll
        for (int i = 0; i < 2; ++i)
            *(uint4*)(smem + OFF_WTH + (i * 512 + tid) * 16) = z;
        __syncthreads();
    }

    // ---- prefetch x fragments before the staging barrier (packed)
    const int nA = (w * 16 + c16 < 100) ? (w * 16 + c16) : 99;
    uint4 xpA[4], xpB[4];
    if (F == 128 && w < 7) {
        const uint* xp = xinP + (size_t)b * 12800 + (size_t)nA * 128 + r16 * 8;
        #pragma unroll
        for (int d = 0; d < 4; ++d) {
            xpA[d] = *(const uint4*)(xp + d * 32);
            xpB[d] = *(const uint4*)(xp + d * 32 + 4);
        }
    }

    // ---- ph1: stage WT (RNE hi/lo, transposed), ASV, AB copy, tail zeroing
    {
        const float4* Wg4 = (const float4*)(W + (size_t)hd * F * 32);
        #pragma unroll
        for (int it = 0; it < 2; ++it) {
            int id = it * 512 + tid;            // F*8 chunks (f, o4)
            if (id < F * 8) {
                int f = id >> 3, o4 = (id & 7) * 4;
                float4 v = Wg4[id];
                ushort h0 = f2bf(v.x), l0 = f2bf(v.x - bf2f(h0));
                ushort h1 = f2bf(v.y), l1 = f2bf(v.y - bf2f(h1));
                ushort h2 = f2bf(v.z), l2 = f2bf(v.z - bf2f(h2));
                ushort h3 = f2bf(v.w), l3 = f2bf(v.w - bf2f(h3));
                *(ushort*)(WTH + swzb(o4 + 0, 2 * f)) = h0; *(ushort*)(WTL + swzb(o4 + 0, 2 * f)) = l0;
                *(ushort*)(WTH + swzb(o4 + 1, 2 * f)) = h1; *(ushort*)(WTL + swzb(o4 + 1, 2 * f)) = l1;
                *(ushort*)(WTH + swzb(o4 + 2, 2 * f)) = h2; *(ushort*)(WTL + swzb(o4 + 2, 2 * f)) = l2;
                *(ushort*)(WTH + swzb(o4 + 3, 2 * f)) = h3; *(ushort*)(WTL + swzb(o4 + 3, 2 * f)) = l3;
            }
        }
    }
    if (tid < 64) ASV[tid] = av[hd * 64 + tid];
    {
        const int idA = tid - 64;
        if (idA >= 0 && idA < 400) ABu[idA] = AW[(size_t)b * 400 + idA];
        else if (idA >= 400 && idA < 448) ABu[idA] = 0u;   // rows 100..111 -> mask 0
    }
    if (tid < 256) {    // zero hT cols 96..127 (96..99 rewritten in ph2)
        char* base = (tid & 128) ? HTL : HTH;
        const int rr = (tid >> 2) & 31, sl = 12 + (tid & 3);
        *(uint4*)(base + swzb(rr, sl * 16)) = make_uint4(0, 0, 0, 0);
    }
    if (tid < 28) { ESV[100 + tid] = 0.f; EDV[100 + tid] = 0.f; }
    __syncthreads();

    // ---- ph2: MFMA-1 h = x*W (wave w owns rows w*16..+15, both o-halves)
    if (w < 7) {
        f32x4 acc0 = {0.f, 0.f, 0.f, 0.f}, acc1 = {0.f, 0.f, 0.f, 0.f};
        #pragma unroll
        for (int d = 0; d < KD; ++d) {
            short8 ah, al;
            if (F == 128) {
                // unpack packed words: 1 perm per output word
                ah = mk8(__builtin_amdgcn_perm(xpA[d].y, xpA[d].x, SEL_H),
                         __builtin_amdgcn_perm(xpA[d].w, xpA[d].z, SEL_H),
                         __builtin_amdgcn_perm(xpB[d].y, xpB[d].x, SEL_H),
                         __builtin_amdgcn_perm(xpB[d].w, xpB[d].z, SEL_H));
                al = mk8(__builtin_amdgcn_perm(xpA[d].y, xpA[d].x, SEL_L),
                         __builtin_amdgcn_perm(xpA[d].w, xpA[d].z, SEL_L),
                         __builtin_amdgcn_perm(xpB[d].y, xpB[d].x, SEL_L),
                         __builtin_amdgcn_perm(xpB[d].w, xpB[d].z, SEL_L));
            } else {
                const float* xg = xinF + (size_t)b * Nn * 65;
                const int f0 = d * 32 + r16 * 8;
                float xv[8];
                #pragma unroll
                for (int j = 0; j < 8; ++j) {
                    int f = f0 + j;
                    xv[j] = (f < 65) ? xg[(size_t)nA * 65 + f] : 0.f;
                }
                uint hu[4], lu[4];
                #pragma unroll
                for (int i = 0; i < 4; ++i) {
                    uint u0 = __float_as_uint(xv[2 * i]);
                    uint u1 = __float_as_uint(xv[2 * i + 1]);
                    float l0 = xv[2 * i]     - __uint_as_float(u0 & 0xFFFF0000u);
                    float l1 = xv[2 * i + 1] - __uint_as_float(u1 & 0xFFFF0000u);
                    hu[i] = __builtin_amdgcn_perm(u1, u0, SEL_L);
                    lu[i] = __builtin_amdgcn_perm(__float_as_uint(l1), __float_as_uint(l0), SEL_L);
                }
                ah = mk8(hu[0], hu[1], hu[2], hu[3]);
                al = mk8(lu[0], lu[1], lu[2], lu[3]);
            }
            const int kb = d * 64 + r16 * 16;
            short8 bh0 = *(const short8*)(WTH + swzb(c16, kb));
            short8 bl0 = *(const short8*)(WTL + swzb(c16, kb));
            short8 bh1 = *(const short8*)(WTH + swzb(16 + c16, kb));
            short8 bl1 = *(const short8*)(WTL + swzb(16 + c16, kb));
            acc0 = __builtin_amdgcn_mfma_f32_16x16x32_bf16(ah, bh0, acc0, 0, 0, 0);
            acc0 = __builtin_amdgcn_mfma_f32_16x16x32_bf16(al, bh0, acc0, 0, 0, 0);
            acc0 = __builtin_amdgcn_mfma_f32_16x16x32_bf16(ah, bl0, acc0, 0, 0, 0);
            acc1 = __builtin_amdgcn_mfma_f32_16x16x32_bf16(ah, bh1, acc1, 0, 0, 0);
            acc1 = __builtin_amdgcn_mfma_f32_16x16x32_bf16(al, bh1, acc1, 0, 0, 0);
            acc1 = __builtin_amdgcn_mfma_f32_16x16x32_bf16(ah, bl1, acc1, 0, 0, 0);
        }
        const int n0 = w * 16 + r16 * 4;
        if (n0 < 100) {   // hT split write: rows o, cols n0..n0+3 (all <100)
            ushort h0 = f2bf(acc0[0]), l0 = f2bf(acc0[0] - bf2f(h0));
            ushort h1 = f2bf(acc0[1]), l1 = f2bf(acc0[1] - bf2f(h1));
            ushort h2 = f2bf(acc0[2]), l2 = f2bf(acc0[2] - bf2f(h2));
            ushort h3 = f2bf(acc0[3]), l3 = f2bf(acc0[3] - bf2f(h3));
            uint2 uh; uh.x = (uint)h0 | ((uint)h1 << 16); uh.y = (uint)h2 | ((uint)h3 << 16);
            uint2 ul; ul.x = (uint)l0 | ((uint)l1 << 16); ul.y = (uint)l2 | ((uint)l3 << 16);
            *(uint2*)(HTH + swzb(c16, 2 * n0)) = uh;
            *(uint2*)(HTL + swzb(c16, 2 * n0)) = ul;
            h0 = f2bf(acc1[0]); l0 = f2bf(acc1[0] - bf2f(h0));
            h1 = f2bf(acc1[1]); l1 = f2bf(acc1[1] - bf2f(h1));
            h2 = f2bf(acc1[2]); l2 = f2bf(acc1[2] - bf2f(h2));
            h3 = f2bf(acc1[3]); l3 = f2bf(acc1[3] - bf2f(h3));
            uh.x = (uint)h0 | ((uint)h1 << 16); uh.y = (uint)h2 | ((uint)h3 << 16);
            ul.x = (uint)l0 | ((uint)l1 << 16); ul.y = (uint)l2 | ((uint)l3 << 16);
            *(uint2*)(HTH + swzb(16 + c16, 2 * n0)) = uh;
            *(uint2*)(HTL + swzb(16 + c16, 2 * n0)) = ul;
        }
        // es/ed: reduce acc*a over 32 o's (both halves pre-summed, 16-lane xor)
        const float as0 = ASV[c16], as1 = ASV[16 + c16];
        const float ad0 = ASV[32 + c16], ad1 = ASV[48 + c16];
        #pragma unroll
        for (int r = 0; r < 4; ++r) {
            float vs = acc0[r] * as0 + acc1[r] * as1;
            float vd = acc0[r] * ad0 + acc1[r] * ad1;
            #pragma unroll
            for (int mk = 1; mk <= 8; mk <<= 1) {
                vs += __shfl_xor(vs, mk, 64);
                vd += __shfl_xor(vd, mk, 64);
            }
            if (c16 == 0 && n0 + r < 100) { ESV[n0 + r] = vs; EDV[n0 + r] = vd; }
        }
    }
    __syncthreads();

    // ---- ph3a: in-register P, MFMA-2 accumulate; rowsum -> INV (LDS)
    f32x4 acc0 = {0.f, 0.f, 0.f, 0.f}, acc1 = {0.f, 0.f, 0.f, 0.f};
    if (w < 7) {
        const int np = w * 16 + c16;            // P-row this lane supplies (<=111)
        const float esn = ESV[np];
        const uint4 abv = *(const uint4*)(ABu + np * 4);
        float rowsum = 0.f;
        #pragma unroll
        for (int d = 0; d < 4; ++d) {
            const uint wrd = (d == 0) ? abv.x : (d == 1) ? abv.y : (d == 2) ? abv.z : abv.w;
            const float4 ea = *(const float4*)(EDV + d * 32 + r16 * 8);
            const float4 eb = *(const float4*)(EDV + d * 32 + r16 * 8 + 4);
            float p0, p1, p2, p3, p4, p5, p6, p7, e;
            e = esn + ea.x; e = e > 0.f ? e : 0.2f * e; p0 = ((wrd >> (r16 * 8 + 0)) & 1u) ? __expf(e) : 0.f;
            e = esn + ea.y; e = e > 0.f ? e : 0.2f * e; p1 = ((wrd >> (r16 * 8 + 1)) & 1u) ? __expf(e) : 0.f;
            e = esn + ea.z; e = e > 0.f ? e : 0.2f * e; p2 = ((wrd >> (r16 * 8 + 2)) & 1u) ? __expf(e) : 0.f;
            e = esn + ea.w; e = e > 0.f ? e : 0.2f * e; p3 = ((wrd >> (r16 * 8 + 3)) & 1u) ? __expf(e) : 0.f;
            e = esn + eb.x; e = e > 0.f ? e : 0.2f * e; p4 = ((wrd >> (r16 * 8 + 4)) & 1u) ? __expf(e) : 0.f;
            e = esn + eb.y; e = e > 0.f ? e : 0.2f * e; p5 = ((wrd >> (r16 * 8 + 5)) & 1u) ? __expf(e) : 0.f;
            e = esn + eb.z; e = e > 0.f ? e : 0.2f * e; p6 = ((wrd >> (r16 * 8 + 6)) & 1u) ? __expf(e) : 0.f;
            e = esn + eb.w; e = e > 0.f ? e : 0.2f * e; p7 = ((wrd >> (r16 * 8 + 7)) & 1u) ? __expf(e) : 0.f;
            rowsum += p0 + p1 + p2 + p3 + p4 + p5 + p6 + p7;
            ushort h0 = f2bf(p0), h1 = f2bf(p1), h2 = f2bf(p2), h3 = f2bf(p3);
            ushort h4 = f2bf(p4), h5 = f2bf(p5), h6 = f2bf(p6), h7 = f2bf(p7);
            ushort q0 = f2bf(p0 - bf2f(h0)), q1 = f2bf(p1 - bf2f(h1));
            ushort q2 = f2bf(p2 - bf2f(h2)), q3 = f2bf(p3 - bf2f(h3));
            ushort q4 = f2bf(p4 - bf2f(h4)), q5 = f2bf(p5 - bf2f(h5));
            ushort q6 = f2bf(p6 - bf2f(h6)), q7 = f2bf(p7 - bf2f(h7));
            short8 ph = mk8((uint)h0 | ((uint)h1 << 16), (uint)h2 | ((uint)h3 << 16),
                            (uint)h4 | ((uint)h5 << 16), (uint)h6 | ((uint)h7 << 16));
            short8 pl = mk8((uint)q0 | ((uint)q1 << 16), (uint)q2 | ((uint)q3 << 16),
                            (uint)q4 | ((uint)q5 << 16), (uint)q6 | ((uint)q7 << 16));
            const int kb = d * 64 + r16 * 16;
            short8 bh0 = *(const short8*)(HTH + swzb(c16, kb));
            short8 bl0 = *(const short8*)(HTL + swzb(c16, kb));
            short8 bh1 = *(const short8*)(HTH + swzb(16 + c16, kb));
            short8 bl1 = *(const short8*)(HTL + swzb(16 + c16, kb));
            acc0 = __builtin_amdgcn_mfma_f32_16x16x32_bf16(ph, bh0, acc0, 0, 0, 0);
            acc0 = __builtin_amdgcn_mfma_f32_16x16x32_bf16(ph, bl0, acc0, 0, 0, 0);
            acc0 = __builtin_amdgcn_mfma_f32_16x16x32_bf16(pl, bh0, acc0, 0, 0, 0);
            acc1 = __builtin_amdgcn_mfma_f32_16x16x32_bf16(ph, bh1, acc1, 0, 0, 0);
            acc1 = __builtin_amdgcn_mfma_f32_16x16x32_bf16(ph, bl1, acc1, 0, 0, 0);
            acc1 = __builtin_amdgcn_mfma_f32_16x16x32_bf16(pl, bh1, acc1, 0, 0, 0);
        }
        rowsum += __shfl_xor(rowsum, 16, 64);
        rowsum += __shfl_xor(rowsum, 32, 64);
        if (r16 == 0 && np < 100) INV[np] = 1.0f / rowsum;
    }
    __syncthreads();

    // ---- ph3b: epilogue elu(acc * inv) -> packed plane (8 u32 stores)
    if (w < 7) {
        const int n0 = w * 16 + r16 * 4;
        uint* xo = outP + (size_t)b * 12800 + hd * 32;
        #pragma unroll
        for (int r = 0; r < 4; ++r) {
            const int n = n0 + r;
            if (n < 100) {
                const float inv = INV[n];
                float v0 = acc0[r] * inv; v0 = v0 > 0.f ? v0 : expm1f(v0);
                float v1 = acc1[r] * inv; v1 = v1 > 0.f ? v1 : expm1f(v1);
                ushort h0 = f2bf(v0), l0 = f2bf(v0 - bf2f(h0));
                ushort h1 = f2bf(v1), l1 = f2bf(v1 - bf2f(h1));
                xo[(size_t)n * 128 + c16]      = (uint)h0 | ((uint)l0 << 16);
                xo[(size_t)n * 128 + 16 + c16] = (uint)h1 | ((uint)l1 << 16);
            }
        }
    }
}

// ---------------------------------------------------------------------------
// GEMM1: A from packed plane (1 perm/word unpack), B fp32 convert,
// 128x128 tile, BK=64, SK=8. R10-proven 1-deep in-place prefetch (no spill).
// ---------------------------------------------------------------------------
#define G1_LDS 73728
__device__ __forceinline__ int aofs(int r, int kb) { return r * 144 + kb; }
__device__ __forceinline__ int bofs(int n, int kb) { return n * 144 + (kb ^ (((n >> 3) & 1) << 4)); }

__global__ __launch_bounds__(512, 4) void gemm1_mfma(
    const uint* __restrict__ APg,
    const float* __restrict__ Bg, float* __restrict__ part)
{
    extern __shared__ char sm[];
    char* AH = sm;             // [128][144]
    char* AL = sm + 18432;
    char* BH = sm + 36864;     // [128][144]
    char* BL = sm + 55296;

    const int tid = threadIdx.x;
    const int pb = blockIdx.x;
    const int task = (pb & 7) * 64 + (pb >> 3);
    const int mb = task & 7, g = task >> 3;
    const int nb = g & 7, z = g >> 3;
    const int m0 = mb * 128, n0 = nb * 128;
    const int k0 = z * 1600;

    const int w = tid >> 6, lane = tid & 63;
    const int wn = w & 3, wm = w >> 2;               // wave tile 64m x 32n
    const int c16 = lane & 15, r16 = lane >> 4;

    const int ra = tid >> 2, kq = tid & 3;           // A: row, 16-k quarter
    const int bn = tid >> 2, kq4 = tid & 3;          // B: col n, 16-k quarter

    const uint*  Ap0 = APg + (size_t)(m0 + ra) * K1 + k0 + kq * 16;
    const float* Bb0 = Bg + ((size_t)k0 + kq4 * 16) * N1 + n0 + bn;

    f32x4 acc[4][2];
    #pragma unroll
    for (int i = 0; i < 4; ++i)
        #pragma unroll
        for (int j = 0; j < 2; ++j) acc[i][j] = (f32x4){0.f, 0.f, 0.f, 0.f};

    // 1-deep prefetch registers (static names, reloaded in place)
    uint4 ap0, ap1, ap2, ap3;
    float bR[16];
    ap0 = *(const uint4*)(Ap0);
    ap1 = *(const uint4*)(Ap0 + 4);
    ap2 = *(const uint4*)(Ap0 + 8);
    ap3 = *(const uint4*)(Ap0 + 12);
    #pragma unroll
    for (int j = 0; j < 16; ++j) bR[j] = Bb0[(size_t)j * N1];

    for (int it = 0; it < 25; ++it) {
        __syncthreads();   // previous iter's MFMA reads done -> LDS writable
        {   // A staging: unpack packed words (1 perm each)
            const int ab = aofs(ra, kq * 32);   // aofs has no XOR: +16 safe
            *(uint4*)(AH + ab) = make_uint4(
                __builtin_amdgcn_perm(ap0.y, ap0.x, SEL_H),
                __builtin_amdgcn_perm(ap0.w, ap0.z, SEL_H),
                __builtin_amdgcn_perm(ap1.y, ap1.x, SEL_H),
                __builtin_amdgcn_perm(ap1.w, ap1.z, SEL_H));
            *(uint4*)(AH + ab + 16) = make_uint4(
                __builtin_amdgcn_perm(ap2.y, ap2.x, SEL_H),
                __builtin_amdgcn_perm(ap2.w, ap2.z, SEL_H),
                __builtin_amdgcn_perm(ap3.y, ap3.x, SEL_H),
                __builtin_amdgcn_perm(ap3.w, ap3.z, SEL_H));
            *(uint4*)(AL + ab) = make_uint4(
                __builtin_amdgcn_perm(ap0.y, ap0.x, SEL_L),
                __builtin_amdgcn_perm(ap0.w, ap0.z, SEL_L),
                __builtin_amdgcn_perm(ap1.y, ap1.x, SEL_L),
                __builtin_amdgcn_perm(ap1.w, ap1.z, SEL_L));
            *(uint4*)(AL + ab + 16) = make_uint4(
                __builtin_amdgcn_perm(ap2.y, ap2.x, SEL_L),
                __builtin_amdgcn_perm(ap2.w, ap2.z, SEL_L),
                __builtin_amdgcn_perm(ap3.y, ap3.x, SEL_L),
                __builtin_amdgcn_perm(ap3.w, ap3.z, SEL_L));
        }
        {   // B staging: trunc split + perm pack
            uint hi[8], lo[8];
            #pragma unroll
            for (int i = 0; i < 8; ++i) {
                uint u0 = __float_as_uint(bR[2 * i]);
                uint u1 = __float_as_uint(bR[2 * i + 1]);
                float l0 = bR[2 * i]     - __uint_as_float(u0 & 0xFFFF0000u);
                float l1 = bR[2 * i + 1] - __uint_as_float(u1 & 0xFFFF0000u);
                hi[i] = __builtin_amdgcn_perm(u1, u0, SEL_L);
                lo[i] = __builtin_amdgcn_perm(__float_as_uint(l1), __float_as_uint(l0), SEL_L);
            }
            const int bb0 = bofs(bn, kq4 * 32);        // swizzle-aware per-16B
            const int bb1 = bofs(bn, kq4 * 32 + 16);
            *(uint4*)(BH + bb0) = make_uint4(hi[0], hi[1], hi[2], hi[3]);
            *(uint4*)(BH + bb1) = make_uint4(hi[4], hi[5], hi[6], hi[7]);
            *(uint4*)(BL + bb0) = make_uint4(lo[0], lo[1], lo[2], lo[3]);
            *(uint4*)(BL + bb1) = make_uint4(lo[4], lo[5], lo[6], lo[7]);
        }
        __syncthreads();   // LDS tile ready

        if (it < 24) {     // prefetch next iter into the same regs
            const int off = (it + 1) * 64;
            ap0 = *(const uint4*)(Ap0 + off);
            ap1 = *(const uint4*)(Ap0 + off + 4);
            ap2 = *(const uint4*)(Ap0 + off + 8);
            ap3 = *(const uint4*)(Ap0 + off + 12);
            #pragma unroll
            for (int j = 0; j < 16; ++j) bR[j] = Bb0[(size_t)(off + j) * N1];
        }

        #pragma unroll
        for (int ks = 0; ks < 2; ++ks) {
            const int kb = ks * 64 + r16 * 16;
            short8 bh[2], bl[2];
            #pragma unroll
            for (int nf = 0; nf < 2; ++nf) {
                const int nr = wn * 32 + nf * 16 + c16;
                bh[nf] = *(const short8*)(BH + bofs(nr, kb));
                bl[nf] = *(const short8*)(BL + bofs(nr, kb));
            }
            #pragma unroll
            for (int mf = 0; mf < 4; ++mf) {
                const int ar = wm * 64 + mf * 16 + c16;
                short8 ah = *(const short8*)(AH + aofs(ar, kb));
                short8 al = *(const short8*)(AL + aofs(ar, kb));
                #pragma unroll
                for (int nf = 0; nf < 2; ++nf) {
                    acc[mf][nf] = __builtin_amdgcn_mfma_f32_16x16x32_bf16(ah, bh[nf], acc[mf][nf], 0, 0, 0);
                    acc[mf][nf] = __builtin_amdgcn_mfma_f32_16x16x32_bf16(al, bh[nf], acc[mf][nf], 0, 0, 0);
                    acc[mf][nf] = __builtin_amdgcn_mfma_f32_16x16x32_bf16(ah, bl[nf], acc[mf][nf], 0, 0, 0);
                }
            }
        }
    }

    float* pz = part + (size_t)z * M1 * N1;
    #pragma unroll
    for (int mf = 0; mf < 4; ++mf) {
        const int m = m0 + wm * 64 + mf * 16 + r16 * 4;
        #pragma unroll
        for (int nf = 0; nf < 2; ++nf) {
            const int n = n0 + wn * 32 + nf * 16 + c16;
            #pragma unroll
            for (int r = 0; r < 4; ++r)
                pz[(size_t)(m + r) * N1 + n] = acc[mf][nf][r];
        }
    }
}

// Reduce split-K partials + bias + BN(eval) + ReLU
__global__ __launch_bounds__(256) void bn1_reduce(
    const float* __restrict__ part, const float* __restrict__ pb1,
    const float* __restrict__ g1, const float* __restrict__ be1,
    float* __restrict__ y1)
{
    const int idx = blockIdx.x * 256 + threadIdx.x;
    float s = 0.f;
    #pragma unroll
    for (int z = 0; z < SK; ++z) s += part[(size_t)z * M1 * N1 + idx];
    const int j = idx & (N1 - 1);
    s += pb1[j];
    const float rbn = 1.0f / sqrtf(1.0f + 1e-5f);
    s = g1[j] * s * rbn + be1[j];
    y1[idx] = fmaxf(s, 0.f);
}

// GEMM2 (1024x1024)x(1024x128) + bias + BN + ReLU -> d_out
__global__ __launch_bounds__(128) void gemm2_bn(
    const float* __restrict__ y1, const float* __restrict__ W2,
    const float* __restrict__ pb2, const float* __restrict__ g2,
    const float* __restrict__ be2, float* __restrict__ out)
{
    __shared__ __align__(16) float xr[1024];
    const int tid = threadIdx.x, m = blockIdx.x;
    for (int i = tid; i < 1024; i += 128) xr[i] = y1[(size_t)m * 1024 + i];
    __syncthreads();
    float acc = 0.f;
    #pragma unroll 8
    for (int k = 0; k < 1024; ++k) acc += xr[k] * W2[k * 128 + tid];
    acc += pb2[tid];
    const float rbn = 1.0f / sqrtf(1.0f + 1e-5f);
    acc = g2[tid] * acc * rbn + be2[tid];
    out[(size_t)m * 128 + tid] = fmaxf(acc, 0.f);
}

// ---------------------------------------------------------------------------
extern "C" void kernel_launch(void* const* d_in, const int* in_sizes, int n_in,
                              void* d_out, int out_size, void* d_ws, size_t ws_size,
                              hipStream_t stream)
{
    const float* X   = (const float*)d_in[0];
    const float* A   = (const float*)d_in[1];
    const float* W0  = (const float*)d_in[2];
    const float* a0  = (const float*)d_in[3];
    const float* Wl  = (const float*)d_in[4];
    const float* al  = (const float*)d_in[5];
    const float* pW1 = (const float*)d_in[6];
    const float* pb1 = (const float*)d_in[7];
    const float* g1  = (const float*)d_in[8];
    const float* be1 = (const float*)d_in[9];
    const float* pW2 = (const float*)d_in[10];
    const float* pb2 = (const float*)d_in[11];
    const float* g2  = (const float*)d_in[12];
    const float* be2 = (const float*)d_in[13];
    float* out = (float*)d_out;

    // ws: xa(52.4MB packed plane) | xb(52.4MB packed plane / gemm1 part) | y1(4.2MB, AW overlay)
    float* ws = (float*)d_ws;
    float* xa = ws;
    float* xb = xa + (size_t)Bb * Nn * Dd;
    float* y1 = xb + (size_t)Bb * Nn * Dd;
    float* part = xb;
    uint*  AW = (uint*)y1;          // packed adjacency, dead before bn1 writes y1
    uint* xaP = (uint*)xa;
    uint* xbP = (uint*)xb;

    (void)hipFuncSetAttribute(reinterpret_cast<const void*>(gat_fused<65, 3>),
                              hipFuncAttributeMaxDynamicSharedMemorySize, GAT_LDS);
    (void)hipFuncSetAttribute(reinterpret_cast<const void*>(gat_fused<128, 4>),
                              hipFuncAttributeMaxDynamicSharedMemorySize, GAT_LDS);
    (void)hipFuncSetAttribute(reinterpret_cast<const void*>(gemm1_mfma),
                              hipFuncAttributeMaxDynamicSharedMemorySize, G1_LDS);

    pack_A<<<dim3(Bb), 256, 0, stream>>>(A, AW);
    // L0: X fp32 -> xa packed plane
    gat_fused<65, 3><<<dim3(Bb * Hh), 512, GAT_LDS, stream>>>(
        X, nullptr, AW, W0, a0, xaP);
    // L1..L4 ping-pong packed planes: xa->xb->xa->xb->xa
    const uint* sP = xaP;
    uint* dP = xbP;
    for (int l = 1; l < 5; ++l) {
        gat_fused<128, 4><<<dim3(Bb * Hh), 512, GAT_LDS, stream>>>(
            nullptr, sP, AW,
            Wl + (size_t)(l - 1) * Hh * Dd * Oo, al + (size_t)(l - 1) * Hh * 2 * Oo, dP);
        uint* t = (uint*)sP; sP = dP; dP = t;
    }
    // after 4 swaps final plane is xaP; xb free for partials
    gemm1_mfma<<<dim3(512), 512, G1_LDS, stream>>>(xaP, pW1, part);
    bn1_reduce<<<dim3((M1 * N1) / 256), 256, 0, stream>>>(part, pb1, g1, be1, y1);
    gemm2_bn<<<dim3(M1), 128, 0, stream>>>(y1, pW2, pb2, g2, be2, out);
}

// Round 15
// 451.056 us; speedup vs baseline: 1.4956x; 1.0935x over previous
//
#include <hip/hip_runtime.h>
#include <math.h>

typedef __attribute__((ext_vector_type(8))) short short8;   // 8 bf16 (4 VGPR) MFMA A/B frag
typedef __attribute__((ext_vector_type(4))) float f32x4;    // MFMA C/D frag
typedef __attribute__((ext_vector_type(4))) uint  uint4v;

constexpr int Bb = 1024, Nn = 100, Hh = 4, Oo = 32, Dd = 128;
constexpr int K1 = 12800, N1 = 1024, M1 = 1024, SK = 8;

#define SEL_L 0x07060302u   /* perm: high ushorts of (b,a) -> packed trunc-bf16 pair */
#define LOG2E 1.44269504f

// bf16 round-to-nearest-even helpers (cold paths only)
__device__ __forceinline__ ushort f2bf(float f) {
    uint u = __float_as_uint(f);
    return (ushort)((u + 0x7FFFu + ((u >> 16) & 1u)) >> 16);
}
__device__ __forceinline__ float bf2f(ushort h) {
    return __uint_as_float(((uint)h) << 16);
}
__device__ __forceinline__ short8 mk8(uint a, uint b, uint c, uint d) {
    uint4v v = {a, b, c, d};
    return __builtin_bit_cast(short8, v);
}
// trunc-split a pair of floats -> packed hi-pair and lo-pair (6 VALU per pair)
__device__ __forceinline__ void tsplit2(float v0, float v1, uint& hp, uint& lp) {
    uint u0 = __float_as_uint(v0), u1 = __float_as_uint(v1);
    float r0 = v0 - __uint_as_float(u0 & 0xFFFF0000u);
    float r1 = v1 - __uint_as_float(u1 & 0xFFFF0000u);
    hp = __builtin_amdgcn_perm(u1, u0, SEL_L);
    lp = __builtin_amdgcn_perm(__float_as_uint(r1), __float_as_uint(r0), SEL_L);
}
// swizzle within [rows][256B] LDS tiles: XOR 16B-slot bits with row&7
__device__ __forceinline__ int swzb(int row, int kb)  { return row * 256 + (kb ^ ((row & 7) << 4)); }

// GAT LDS layout (dynamic, 36352 B)
#define OFF_HTH 0        /* hT hi [32][256B] */
#define OFF_HTL 8192
#define OFF_WTH 16384    /* WT hi [32][256B] */
#define OFF_WTL 24576
#define OFF_AB  32768    /* adjacency bitmask [112][4 u32] (448 words, >=400 zeroed) */
#define OFF_ASV 34560    /* a-vector 64 f32 (pre-scaled by log2 e) */
#define OFF_ESV 34816    /* e_src [128] f32 */
#define OFF_EDV 35328    /* e_dst [128] f32 */
#define OFF_INV 35840    /* 1/rowsum [128] f32 */
#define GAT_LDS 36352

// ---------------------------------------------------------------------------
// pack_A: adjacency -> 128-bit masks, once per b (not per head).
// ---------------------------------------------------------------------------
__global__ __launch_bounds__(256) void pack_A(const float* __restrict__ A, uint* __restrict__ AW)
{
    const int b = blockIdx.x;
    const float4* Ab = (const float4*)(A + (size_t)b * 10000);
    for (int t = threadIdx.x; t < 400; t += 256) {
        const int row = t >> 2, word = t & 3;
        uint bits = 0;
        if (word < 3) {
            #pragma unroll
            for (int j = 0; j < 8; ++j) {
                float4 v = Ab[row * 25 + word * 8 + j];
                uint b4 = (v.x > 0.f ? 1u : 0u) | (v.y > 0.f ? 2u : 0u)
                        | (v.z > 0.f ? 4u : 0u) | (v.w > 0.f ? 8u : 0u);
                bits |= b4 << (j * 4);
            }
        } else {
            float4 v = Ab[row * 25 + 24];   // cols 96..99; 100..127 stay 0
            bits = (v.x > 0.f ? 1u : 0u) | (v.y > 0.f ? 2u : 0u)
                 | (v.z > 0.f ? 4u : 0u) | (v.w > 0.f ? 8u : 0u);
        }
        AW[(size_t)b * 400 + t] = bits;
    }
}

// ---------------------------------------------------------------------------
// Fused GAT layer v3.2 (= R10 structure + trunc-split packing + exp2):
//   per (b, head) block, 512 thr, 3 barriers; in-register P -> MFMA-2.
// ---------------------------------------------------------------------------
template<int F, int KD>
__global__ __launch_bounds__(512, 4) void gat_fused(
    const float* __restrict__ xin,   // [B][100][F]
    const uint*  __restrict__ AW,    // [B][100][4] packed adjacency
    const float* __restrict__ W,     // [H][F][32]
    const float* __restrict__ av,    // [H][64]
    float* __restrict__ xout)        // [B][100][128]
{
    extern __shared__ char smem[];
    char*  HTH = smem + OFF_HTH;
    char*  HTL = smem + OFF_HTL;
    char*  WTH = smem + OFF_WTH;
    char*  WTL = smem + OFF_WTL;
    uint*  ABu = (uint*)(smem + OFF_AB);
    float* ASV = (float*)(smem + OFF_ASV);
    float* ESV = (float*)(smem + OFF_ESV);
    float* EDV = (float*)(smem + OFF_EDV);
    float* INV = (float*)(smem + OFF_INV);

    const int tid = threadIdx.x;
    // XCD-grouped swizzle: 4 head-blocks of one b land on one XCD, adjacent slots
    const int task = (blockIdx.x & 7) * 512 + (blockIdx.x >> 3);
    const int b = task >> 2, hd = task & 3;
    const int w = tid >> 6, lane = tid & 63;
    const int c16 = lane & 15, r16 = lane >> 4;

    const float* xg = xin + (size_t)b * Nn * F;

    if (F == 65) {   // zero WT for k-padding (f 65..95)
        uint4 z = make_uint4(0, 0, 0, 0);
        #pragma unroll
        for (int i = 0; i < 2; ++i)
            *(uint4*)(smem + OFF_WTH + (i * 512 + tid) * 16) = z;
        __syncthreads();
    }

    // ---- prefetch x fragments (F=128 path) before the staging barrier
    const int nA = (w * 16 + c16 < 100) ? (w * 16 + c16) : 99;
    float4 xpre[8];
    if (F == 128 && w < 7) {
        #pragma unroll
        for (int d = 0; d < 4; ++d) {
            const float* px = xg + (size_t)nA * 128 + d * 32 + r16 * 8;
            xpre[2 * d]     = *(const float4*)(px);
            xpre[2 * d + 1] = *(const float4*)(px + 4);
        }
    }

    // ---- ph1: stage WT (RNE hi/lo, transposed; cold), ASV (pre-scaled), AB, zero tails
    {
        const float4* Wg4 = (const float4*)(W + (size_t)hd * F * 32);
        #pragma unroll
        for (int it = 0; it < 2; ++it) {
            int id = it * 512 + tid;            // F*8 chunks (f, o4)
            if (id < F * 8) {
                int f = id >> 3, o4 = (id & 7) * 4;
                float4 v = Wg4[id];
                ushort h0 = f2bf(v.x), l0 = f2bf(v.x - bf2f(h0));
                ushort h1 = f2bf(v.y), l1 = f2bf(v.y - bf2f(h1));
                ushort h2 = f2bf(v.z), l2 = f2bf(v.z - bf2f(h2));
                ushort h3 = f2bf(v.w), l3 = f2bf(v.w - bf2f(h3));
                *(ushort*)(WTH + swzb(o4 + 0, 2 * f)) = h0; *(ushort*)(WTL + swzb(o4 + 0, 2 * f)) = l0;
                *(ushort*)(WTH + swzb(o4 + 1, 2 * f)) = h1; *(ushort*)(WTL + swzb(o4 + 1, 2 * f)) = l1;
                *(ushort*)(WTH + swzb(o4 + 2, 2 * f)) = h2; *(ushort*)(WTL + swzb(o4 + 2, 2 * f)) = l2;
                *(ushort*)(WTH + swzb(o4 + 3, 2 * f)) = h3; *(ushort*)(WTL + swzb(o4 + 3, 2 * f)) = l3;
            }
        }
    }
    if (tid < 64) ASV[tid] = av[hd * 64 + tid] * LOG2E;   // fold exp->exp2 scale
    {
        const int idA = tid - 64;
        if (idA >= 0 && idA < 400) ABu[idA] = AW[(size_t)b * 400 + idA];
        else if (idA >= 400 && idA < 448) ABu[idA] = 0u;   // rows 100..111 -> mask 0
    }
    if (tid < 256) {    // zero hT cols 96..127 (96..99 rewritten in ph2)
        char* base = (tid & 128) ? HTL : HTH;
        const int rr = (tid >> 2) & 31, sl = 12 + (tid & 3);
        *(uint4*)(base + swzb(rr, sl * 16)) = make_uint4(0, 0, 0, 0);
    }
    if (tid < 28) { ESV[100 + tid] = 0.f; EDV[100 + tid] = 0.f; }
    __syncthreads();

    // ---- ph2: MFMA-1 h = x*W (wave w owns rows w*16..+15, both o-halves)
    if (w < 7) {
        f32x4 acc0 = {0.f, 0.f, 0.f, 0.f}, acc1 = {0.f, 0.f, 0.f, 0.f};
        #pragma unroll
        for (int d = 0; d < KD; ++d) {
            float xv[8];
            if (F == 128) {
                float4 v0 = xpre[2 * d], v1 = xpre[2 * d + 1];
                xv[0] = v0.x; xv[1] = v0.y; xv[2] = v0.z; xv[3] = v0.w;
                xv[4] = v1.x; xv[5] = v1.y; xv[6] = v1.z; xv[7] = v1.w;
            } else {
                const int f0 = d * 32 + r16 * 8;
                #pragma unroll
                for (int j = 0; j < 8; ++j) {
                    int f = f0 + j;
                    xv[j] = (f < 65) ? xg[(size_t)nA * 65 + f] : 0.f;
                }
            }
            uint hu[4], lu[4];
            tsplit2(xv[0], xv[1], hu[0], lu[0]);
            tsplit2(xv[2], xv[3], hu[1], lu[1]);
            tsplit2(xv[4], xv[5], hu[2], lu[2]);
            tsplit2(xv[6], xv[7], hu[3], lu[3]);
            short8 ah = mk8(hu[0], hu[1], hu[2], hu[3]);
            short8 al = mk8(lu[0], lu[1], lu[2], lu[3]);
            const int kb = d * 64 + r16 * 16;
            short8 bh0 = *(const short8*)(WTH + swzb(c16, kb));
            short8 bl0 = *(const short8*)(WTL + swzb(c16, kb));
            short8 bh1 = *(const short8*)(WTH + swzb(16 + c16, kb));
            short8 bl1 = *(const short8*)(WTL + swzb(16 + c16, kb));
            acc0 = __builtin_amdgcn_mfma_f32_16x16x32_bf16(ah, bh0, acc0, 0, 0, 0);
            acc0 = __builtin_amdgcn_mfma_f32_16x16x32_bf16(al, bh0, acc0, 0, 0, 0);
            acc0 = __builtin_amdgcn_mfma_f32_16x16x32_bf16(ah, bl0, acc0, 0, 0, 0);
            acc1 = __builtin_amdgcn_mfma_f32_16x16x32_bf16(ah, bh1, acc1, 0, 0, 0);
            acc1 = __builtin_amdgcn_mfma_f32_16x16x32_bf16(al, bh1, acc1, 0, 0, 0);
            acc1 = __builtin_amdgcn_mfma_f32_16x16x32_bf16(ah, bl1, acc1, 0, 0, 0);
        }
        const int n0 = w * 16 + r16 * 4;
        if (n0 < 100) {   // hT trunc-split write: rows o, cols n0..n0+3
            uint2 uh, ul;
            tsplit2(acc0[0], acc0[1], uh.x, ul.x);
            tsplit2(acc0[2], acc0[3], uh.y, ul.y);
            *(uint2*)(HTH + swzb(c16, 2 * n0)) = uh;
            *(uint2*)(HTL + swzb(c16, 2 * n0)) = ul;
            tsplit2(acc1[0], acc1[1], uh.x, ul.x);
            tsplit2(acc1[2], acc1[3], uh.y, ul.y);
            *(uint2*)(HTH + swzb(16 + c16, 2 * n0)) = uh;
            *(uint2*)(HTL + swzb(16 + c16, 2 * n0)) = ul;
        }
        // es/ed: reduce acc*a over 32 o's (both halves pre-summed, 16-lane xor)
        const float as0 = ASV[c16], as1 = ASV[16 + c16];
        const float ad0 = ASV[32 + c16], ad1 = ASV[48 + c16];
        #pragma unroll
        for (int r = 0; r < 4; ++r) {
            float vs = acc0[r] * as0 + acc1[r] * as1;
            float vd = acc0[r] * ad0 + acc1[r] * ad1;
            #pragma unroll
            for (int mk = 1; mk <= 8; mk <<= 1) {
                vs += __shfl_xor(vs, mk, 64);
                vd += __shfl_xor(vd, mk, 64);
            }
            if (c16 == 0 && n0 + r < 100) { ESV[n0 + r] = vs; EDV[n0 + r] = vd; }
        }
    }
    __syncthreads();

    // ---- ph3a: in-register P (exp2, trunc-split), MFMA-2; rowsum -> INV (LDS)
    f32x4 acc0 = {0.f, 0.f, 0.f, 0.f}, acc1 = {0.f, 0.f, 0.f, 0.f};
    if (w < 7) {
        const int np = w * 16 + c16;            // P-row this lane supplies (<=111)
        const float esn = ESV[np];
        const uint4 abv = *(const uint4*)(ABu + np * 4);
        float rowsum = 0.f;
        #pragma unroll
        for (int d = 0; d < 4; ++d) {
            const uint wrd = (d == 0) ? abv.x : (d == 1) ? abv.y : (d == 2) ? abv.z : abv.w;
            const float4 ea = *(const float4*)(EDV + d * 32 + r16 * 8);
            const float4 eb = *(const float4*)(EDV + d * 32 + r16 * 8 + 4);
            float p0, p1, p2, p3, p4, p5, p6, p7, e;
            e = esn + ea.x; e = fmaxf(e, 0.2f * e); p0 = ((wrd >> (r16 * 8 + 0)) & 1u) ? exp2f(e) : 0.f;
            e = esn + ea.y; e = fmaxf(e, 0.2f * e); p1 = ((wrd >> (r16 * 8 + 1)) & 1u) ? exp2f(e) : 0.f;
            e = esn + ea.z; e = fmaxf(e, 0.2f * e); p2 = ((wrd >> (r16 * 8 + 2)) & 1u) ? exp2f(e) : 0.f;
            e = esn + ea.w; e = fmaxf(e, 0.2f * e); p3 = ((wrd >> (r16 * 8 + 3)) & 1u) ? exp2f(e) : 0.f;
            e = esn + eb.x; e = fmaxf(e, 0.2f * e); p4 = ((wrd >> (r16 * 8 + 4)) & 1u) ? exp2f(e) : 0.f;
            e = esn + eb.y; e = fmaxf(e, 0.2f * e); p5 = ((wrd >> (r16 * 8 + 5)) & 1u) ? exp2f(e) : 0.f;
            e = esn + eb.z; e = fmaxf(e, 0.2f * e); p6 = ((wrd >> (r16 * 8 + 6)) & 1u) ? exp2f(e) : 0.f;
            e = esn + eb.w; e = fmaxf(e, 0.2f * e); p7 = ((wrd >> (r16 * 8 + 7)) & 1u) ? exp2f(e) : 0.f;
            rowsum += p0 + p1 + p2 + p3 + p4 + p5 + p6 + p7;
            uint h01, l01, h23, l23, h45, l45, h67, l67;
            tsplit2(p0, p1, h01, l01);
            tsplit2(p2, p3, h23, l23);
            tsplit2(p4, p5, h45, l45);
            tsplit2(p6, p7, h67, l67);
            short8 ph = mk8(h01, h23, h45, h67);
            short8 pl = mk8(l01, l23, l45, l67);
            const int kb = d * 64 + r16 * 16;
            short8 bh0 = *(const short8*)(HTH + swzb(c16, kb));
            short8 bl0 = *(const short8*)(HTL + swzb(c16, kb));
            short8 bh1 = *(const short8*)(HTH + swzb(16 + c16, kb));
            short8 bl1 = *(const short8*)(HTL + swzb(16 + c16, kb));
            acc0 = __builtin_amdgcn_mfma_f32_16x16x32_bf16(ph, bh0, acc0, 0, 0, 0);
            acc0 = __builtin_amdgcn_mfma_f32_16x16x32_bf16(ph, bl0, acc0, 0, 0, 0);
            acc0 = __builtin_amdgcn_mfma_f32_16x16x32_bf16(pl, bh0, acc0, 0, 0, 0);
            acc1 = __builtin_amdgcn_mfma_f32_16x16x32_bf16(ph, bh1, acc1, 0, 0, 0);
            acc1 = __builtin_amdgcn_mfma_f32_16x16x32_bf16(ph, bl1, acc1, 0, 0, 0);
            acc1 = __builtin_amdgcn_mfma_f32_16x16x32_bf16(pl, bh1, acc1, 0, 0, 0);
        }
        rowsum += __shfl_xor(rowsum, 16, 64);
        rowsum += __shfl_xor(rowsum, 32, 64);
        if (r16 == 0 && np < 100) INV[np] = 1.0f / rowsum;
    }
    __syncthreads();

    // ---- ph3b: epilogue elu(acc * inv) -> global fp32
    if (w < 7) {
        const int n0 = w * 16 + r16 * 4;
        float* xo = xout + (size_t)b * Nn * Dd + hd * 32;
        #pragma unroll
        for (int r = 0; r < 4; ++r) {
            const int n = n0 + r;
            if (n < 100) {
                const float inv = INV[n];
                float v0 = acc0[r] * inv; v0 = v0 > 0.f ? v0 : expm1f(v0);
                float v1 = acc1[r] * inv; v1 = v1 > 0.f ? v1 : expm1f(v1);
                xo[(size_t)n * Dd + c16] = v0;
                xo[(size_t)n * Dd + 16 + c16] = v1;
            }
        }
    }
}

// ---------------------------------------------------------------------------
// GEMM1 split-bf16 MFMA (R10-exact, proven 130us @ 52 VGPR):
// 128x128 tile, BK=64, SK=8, 1-deep in-place prefetch.
// ---------------------------------------------------------------------------
#define G1_LDS 73728
__device__ __forceinline__ int aofs(int r, int kb) { return r * 144 + kb; }
__device__ __forceinline__ int bofs(int n, int kb) { return n * 144 + (kb ^ (((n >> 3) & 1) << 4)); }

__global__ __launch_bounds__(512, 4) void gemm1_mfma(
    const float* __restrict__ Ag, const float* __restrict__ Bg,
    float* __restrict__ part)
{
    extern __shared__ char sm[];
    char* AH = sm;             // [128][144]
    char* AL = sm + 18432;
    char* BH = sm + 36864;     // [128][144]
    char* BL = sm + 55296;

    const int tid = threadIdx.x;
    const int pb = blockIdx.x;
    const int task = (pb & 7) * 64 + (pb >> 3);
    const int mb = task & 7, g = task >> 3;
    const int nb = g & 7, z = g >> 3;
    const int m0 = mb * 128, n0 = nb * 128;
    const int k0 = z * 1600;

    const int w = tid >> 6, lane = tid & 63;
    const int wn = w & 3, wm = w >> 2;               // wave tile 64m x 32n
    const int c16 = lane & 15, r16 = lane >> 4;

    const int ra = tid >> 2, kq = tid & 3;           // A: row, 16-k quarter
    const int bn = tid >> 2, kq4 = tid & 3;          // B: col n, 16-k quarter

    const float* Aptr = Ag + (size_t)(m0 + ra) * K1 + k0 + kq * 16;
    const float* Bptr = Bg + (size_t)(k0 + kq4 * 16) * N1 + n0 + bn;

    f32x4 acc[4][2];
    #pragma unroll
    for (int i = 0; i < 4; ++i)
        #pragma unroll
        for (int j = 0; j < 2; ++j) acc[i][j] = (f32x4){0.f, 0.f, 0.f, 0.f};

    float a_reg[16];
    float bR[16];
    #pragma unroll
    for (int q = 0; q < 4; ++q) *(float4*)&a_reg[q * 4] = *(const float4*)(Aptr + q * 4);
    #pragma unroll
    for (int j = 0; j < 16; ++j) bR[j] = Bptr[(size_t)j * N1];

    for (int it = 0; it < 25; ++it) {
        __syncthreads();   // previous iter's MFMA reads done -> LDS writable
        {   // A staging: trunc split + perm pack
            uint hi[8], lo[8];
            #pragma unroll
            for (int i = 0; i < 8; ++i) tsplit2(a_reg[2 * i], a_reg[2 * i + 1], hi[i], lo[i]);
            const int ab = aofs(ra, kq * 32);   // aofs has no XOR: +16 safe
            *(uint4*)(AH + ab)      = make_uint4(hi[0], hi[1], hi[2], hi[3]);
            *(uint4*)(AH + ab + 16) = make_uint4(hi[4], hi[5], hi[6], hi[7]);
            *(uint4*)(AL + ab)      = make_uint4(lo[0], lo[1], lo[2], lo[3]);
            *(uint4*)(AL + ab + 16) = make_uint4(lo[4], lo[5], lo[6], lo[7]);
        }
        {   // B staging: trunc split + perm pack (swizzle-aware per-16B)
            uint hi[8], lo[8];
            #pragma unroll
            for (int i = 0; i < 8; ++i) tsplit2(bR[2 * i], bR[2 * i + 1], hi[i], lo[i]);
            const int bb0 = bofs(bn, kq4 * 32);
            const int bb1 = bofs(bn, kq4 * 32 + 16);
            *(uint4*)(BH + bb0) = make_uint4(hi[0], hi[1], hi[2], hi[3]);
            *(uint4*)(BH + bb1) = make_uint4(hi[4], hi[5], hi[6], hi[7]);
            *(uint4*)(BL + bb0) = make_uint4(lo[0], lo[1], lo[2], lo[3]);
            *(uint4*)(BL + bb1) = make_uint4(lo[4], lo[5], lo[6], lo[7]);
        }
        __syncthreads();   // LDS tile ready

        if (it < 24) {     // prefetch next iter into the same regs
            const int off = (it + 1) * 64;
            #pragma unroll
            for (int q = 0; q < 4; ++q) *(float4*)&a_reg[q * 4] = *(const float4*)(Aptr + off + q * 4);
            #pragma unroll
            for (int j = 0; j < 16; ++j) bR[j] = Bptr[(size_t)(off + j) * N1];
        }

        #pragma unroll
        for (int ks = 0; ks < 2; ++ks) {
            const int kb = ks * 64 + r16 * 16;
            short8 bh[2], bl[2];
            #pragma unroll
            for (int nf = 0; nf < 2; ++nf) {
                const int nr = wn * 32 + nf * 16 + c16;
                bh[nf] = *(const short8*)(BH + bofs(nr, kb));
                bl[nf] = *(const short8*)(BL + bofs(nr, kb));
            }
            #pragma unroll
            for (int mf = 0; mf < 4; ++mf) {
                const int ar = wm * 64 + mf * 16 + c16;
                short8 ah = *(const short8*)(AH + aofs(ar, kb));
                short8 al = *(const short8*)(AL + aofs(ar, kb));
                #pragma unroll
                for (int nf = 0; nf < 2; ++nf) {
                    acc[mf][nf] = __builtin_amdgcn_mfma_f32_16x16x32_bf16(ah, bh[nf], acc[mf][nf], 0, 0, 0);
                    acc[mf][nf] = __builtin_amdgcn_mfma_f32_16x16x32_bf16(al, bh[nf], acc[mf][nf], 0, 0, 0);
                    acc[mf][nf] = __builtin_amdgcn_mfma_f32_16x16x32_bf16(ah, bl[nf], acc[mf][nf], 0, 0, 0);
                }
            }
        }
    }

    float* pz = part + (size_t)z * M1 * N1;
    #pragma unroll
    for (int mf = 0; mf < 4; ++mf) {
        const int m = m0 + wm * 64 + mf * 16 + r16 * 4;
        #pragma unroll
        for (int nf = 0; nf < 2; ++nf) {
            const int n = n0 + wn * 32 + nf * 16 + c16;
            #pragma unroll
            for (int r = 0; r < 4; ++r)
                pz[(size_t)(m + r) * N1 + n] = acc[mf][nf][r];
        }
    }
}

// Reduce split-K partials + bias + BN(eval) + ReLU
__global__ __launch_bounds__(256) void bn1_reduce(
    const float* __restrict__ part, const float* __restrict__ pb1,
    const float* __restrict__ g1, const float* __restrict__ be1,
    float* __restrict__ y1)
{
    const int idx = blockIdx.x * 256 + threadIdx.x;
    float s = 0.f;
    #pragma unroll
    for (int z = 0; z < SK; ++z) s += part[(size_t)z * M1 * N1 + idx];
    const int j = idx & (N1 - 1);
    s += pb1[j];
    const float rbn = 1.0f / sqrtf(1.0f + 1e-5f);
    s = g1[j] * s * rbn + be1[j];
    y1[idx] = fmaxf(s, 0.f);
}

// GEMM2 (1024x1024)x(1024x128) + bias + BN + ReLU -> d_out
__global__ __launch_bounds__(128) void gemm2_bn(
    const float* __restrict__ y1, const float* __restrict__ W2,
    const float* __restrict__ pb2, const float* __restrict__ g2,
    const float* __restrict__ be2, float* __restrict__ out)
{
    __shared__ __align__(16) float xr[1024];
    const int tid = threadIdx.x, m = blockIdx.x;
    for (int i = tid; i < 1024; i += 128) xr[i] = y1[(size_t)m * 1024 + i];
    __syncthreads();
    float acc = 0.f;
    #pragma unroll 8
    for (int k = 0; k < 1024; ++k) acc += xr[k] * W2[k * 128 + tid];
    acc += pb2[tid];
    const float rbn = 1.0f / sqrtf(1.0f + 1e-5f);
    acc = g2[tid] * acc * rbn + be2[tid];
    out[(size_t)m * 128 + tid] = fmaxf(acc, 0.f);
}

// ---------------------------------------------------------------------------
extern "C" void kernel_launch(void* const* d_in, const int* in_sizes, int n_in,
                              void* d_out, int out_size, void* d_ws, size_t ws_size,
                              hipStream_t stream)
{
    const float* X   = (const float*)d_in[0];
    const float* A   = (const float*)d_in[1];
    const float* W0  = (const float*)d_in[2];
    const float* a0  = (const float*)d_in[3];
    const float* Wl  = (const float*)d_in[4];
    const float* al  = (const float*)d_in[5];
    const float* pW1 = (const float*)d_in[6];
    const float* pb1 = (const float*)d_in[7];
    const float* g1  = (const float*)d_in[8];
    const float* be1 = (const float*)d_in[9];
    const float* pW2 = (const float*)d_in[10];
    const float* pb2 = (const float*)d_in[11];
    const float* g2  = (const float*)d_in[12];
    const float* be2 = (const float*)d_in[13];
    float* out = (float*)d_out;

    // ws: xa(52.4MB) | xb(52.4MB, reused as gemm1 partials) | y1(4.2MB, AW overlay)
    float* ws = (float*)d_ws;
    float* xa = ws;
    float* xb = xa + (size_t)Bb * Nn * Dd;
    float* y1 = xb + (size_t)Bb * Nn * Dd;
    float* part = xb;
    uint*  AW = (uint*)y1;          // packed adjacency, dead before bn1 writes y1

    (void)hipFuncSetAttribute(reinterpret_cast<const void*>(gat_fused<65, 3>),
                              hipFuncAttributeMaxDynamicSharedMemorySize, GAT_LDS);
    (void)hipFuncSetAttribute(reinterpret_cast<const void*>(gat_fused<128, 4>),
                              hipFuncAttributeMaxDynamicSharedMemorySize, GAT_LDS);
    (void)hipFuncSetAttribute(reinterpret_cast<const void*>(gemm1_mfma),
                              hipFuncAttributeMaxDynamicSharedMemorySize, G1_LDS);

    pack_A<<<dim3(Bb), 256, 0, stream>>>(A, AW);
    gat_fused<65, 3><<<dim3(Bb * Hh), 512, GAT_LDS, stream>>>(X, AW, W0, a0, xa);
    const float* src = xa; float* dst = xb;
    for (int l = 1; l < 5; ++l) {
        gat_fused<128, 4><<<dim3(Bb * Hh), 512, GAT_LDS, stream>>>(
            src, AW, Wl + (size_t)(l - 1) * Hh * Dd * Oo, al + (size_t)(l - 1) * Hh * 2 * Oo, dst);
        float* t = (float*)src; src = dst; dst = t;
    }
    // after 4 swaps final GAT output is xa; xb free for partials
    gemm1_mfma<<<dim3(512), 512, G1_LDS, stream>>>(xa, pW1, part);
    bn1_reduce<<<dim3((M1 * N1) / 256), 256, 0, stream>>>(part, pb1, g1, be1, y1);
    gemm2_bn<<<dim3(M1), 128, 0, stream>>>(y1, pW2, pb2, g2, be2, out);
}